// Round 4
// baseline (4207.523 us; speedup 1.0000x reference)
//
#include <hip/hip_runtime.h>
#include <cmath>

#define B_ 8
#define Q_ 100
#define D_ 256
#define H_ 8
#define HD_ 32
#define L_ 9
#define F_ 2048
#define C_ 151
#define HM_ 112
#define PMAX_ 3136
#define QT_ 32
#define KT_ 128

#define KBLK4 1

typedef __attribute__((ext_vector_type(4))) short s4v;
typedef __attribute__((ext_vector_type(8))) short s8v;
typedef __attribute__((ext_vector_type(4))) float f4v;

__device__ __forceinline__ unsigned short f2bf(float x) {
  unsigned int u = __float_as_uint(x);
  return (unsigned short)((u + 0x7fffu + ((u >> 16) & 1u)) >> 16);
}
__device__ __forceinline__ float bf2f(unsigned short h) {
  return __uint_as_float(((unsigned int)h) << 16);
}
__device__ __forceinline__ void split2(float x, short& h, short& l) {
  unsigned short hb = f2bf(x);
  float r = x - bf2f(hb);
  h = (short)hb;
  l = (short)f2bf(r);
}

// ---------------- block reductions (256 threads) ----------------
__device__ __forceinline__ float block_sum(float v, float* red) {
  int t = threadIdx.x;
  red[t] = v; __syncthreads();
  for (int s = 128; s > 0; s >>= 1) {
    if (t < s) red[t] += red[t + s];
    __syncthreads();
  }
  float r = red[0]; __syncthreads();
  return r;
}

// ---------------- init q ----------------
__global__ __launch_bounds__(256) void initq_kernel(const float* __restrict__ qf,
                                                    const float* __restrict__ qe,
                                                    float* __restrict__ q) {
  int idx = blockIdx.x * 256 + threadIdx.x;
  int qd = idx % (Q_ * D_);
  q[idx] = qf[qd] + qe[qd];
}

// ---------------- transpose-split: fp32 [K][N] -> bf16 [N][2K] ----------------
__global__ __launch_bounds__(256) void tsplit_kernel(
    const float* __restrict__ in, short* __restrict__ out,
    int K, int N, long long ibs, long long obs) {
  __shared__ float tile[32][33];
  const int z = blockIdx.z;
  const int nb = blockIdx.x * 32, kb = blockIdx.y * 32;
  const float* I = in + (size_t)z * ibs;
  short* O = out + (size_t)z * obs;
  const int t = threadIdx.x;
  {
    const int r = t >> 3, c = (t & 7) * 4;
    const int gk = kb + r;
#pragma unroll
    for (int j = 0; j < 4; ++j) {
      int gn = nb + c + j;
      tile[r][c + j] = (gk < K && gn < N) ? I[(size_t)gk * N + gn] : 0.f;
    }
  }
  __syncthreads();
  {
    const int nr = t >> 3, kc = (t & 7) * 4;
    const int gn = nb + nr;
    if (gn < N) {
#pragma unroll
      for (int j = 0; j < 4; ++j) {
        int gk = kb + kc + j;
        if (gk < K) {
          short h, l; split2(tile[kc + j][nr], h, l);
          O[(size_t)gn * 2 * K + gk] = h;
          O[(size_t)gn * 2 * K + K + gk] = l;
        }
      }
    }
  }
}

// ---------------- MFMA bf16x3 GEMM ----------------
__device__ __forceinline__ s8v ldfrag(const short* p) {
#if KBLK4
  s4v lo = *(const s4v*)p;
  s4v hi = *(const s4v*)(p + 16);
  return __builtin_shufflevector(lo, hi, 0, 1, 2, 3, 4, 5, 6, 7);
#else
  s4v lo = *(const s4v*)p;
  s4v hi = *(const s4v*)(p + 4);
  return __builtin_shufflevector(lo, hi, 0, 1, 2, 3, 4, 5, 6, 7);
#endif
}

// OUT: 0 = fp32 store, 1 = bf16 store
template <int AMODE, int WMODE, bool RELU, int OUT>
__global__ __launch_bounds__(256) void mgemm_kernel(
    const void* __restrict__ Ap, const void* __restrict__ Wp,
    const float* __restrict__ bias, void* __restrict__ Cv,
    int M, int N, int K,
    long long Abs, long long Wbs, long long Cbs, int ldc) {
  __shared__ short Ah[64 * 36], Al[64 * 36], Wh[128 * 36], Wl[128 * 36];
  const int z = blockIdx.z;
  const int n0 = blockIdx.x * 128, m0 = blockIdx.y * 64;
  const int t = threadIdx.x;
  const int lane = t & 63;
  const int wave = t >> 6;
  const int wm = wave >> 1, wn = wave & 1;
  const int lr = lane & 15, lg = lane >> 4;
  f4v acc[2][4];
#pragma unroll
  for (int i = 0; i < 2; ++i)
#pragma unroll
    for (int j = 0; j < 4; ++j) acc[i][j] = (f4v){0.f, 0.f, 0.f, 0.f};

  const int arow = t >> 2;

  for (int k0 = 0; k0 < K; k0 += 32) {
    if (AMODE == 0) {
      const float* A = (const float*)Ap + (size_t)z * Abs;
      const int kc = (t & 3) * 8;
      float x[8];
      if (m0 + arow < M) {
        const float* ap = A + (size_t)(m0 + arow) * K + k0 + kc;
        *(f4v*)&x[0] = *(const f4v*)ap;
        *(f4v*)&x[4] = *(const f4v*)(ap + 4);
      } else {
#pragma unroll
        for (int e = 0; e < 8; ++e) x[e] = 0.f;
      }
      s4v h0, h1, l0, l1;
#pragma unroll
      for (int e = 0; e < 4; ++e) { short hh, ll; split2(x[e], hh, ll); h0[e] = hh; l0[e] = ll; }
#pragma unroll
      for (int e = 0; e < 4; ++e) { short hh, ll; split2(x[4 + e], hh, ll); h1[e] = hh; l1[e] = ll; }
      *(s4v*)&Ah[arow * 36 + kc] = h0; *(s4v*)&Ah[arow * 36 + kc + 4] = h1;
      *(s4v*)&Al[arow * 36 + kc] = l0; *(s4v*)&Al[arow * 36 + kc + 4] = l1;
    } else {
      const short* A2 = (const short*)Ap + (size_t)z * Abs;
      const int c = t & 3, sel = c >> 1, ko = (c & 1) * 16;
      s8v v0 = {0, 0, 0, 0, 0, 0, 0, 0}, v1 = {0, 0, 0, 0, 0, 0, 0, 0};
      if (m0 + arow < M) {
        const short* ap = A2 + (size_t)(m0 + arow) * (2 * K) + sel * K + k0 + ko;
        v0 = *(const s8v*)ap;
        v1 = *(const s8v*)(ap + 8);
      }
      short* dst = sel ? Al : Ah;
      *(s4v*)&dst[arow * 36 + ko] = __builtin_shufflevector(v0, v0, 0, 1, 2, 3);
      *(s4v*)&dst[arow * 36 + ko + 4] = __builtin_shufflevector(v0, v0, 4, 5, 6, 7);
      *(s4v*)&dst[arow * 36 + ko + 8] = __builtin_shufflevector(v1, v1, 0, 1, 2, 3);
      *(s4v*)&dst[arow * 36 + ko + 12] = __builtin_shufflevector(v1, v1, 4, 5, 6, 7);
    }
    if (WMODE == 0) {
      const short* W2 = (const short*)Wp + (size_t)z * Wbs;
      const int n = t >> 1, sel = t & 1;
      const short* wp = W2 + (size_t)(n0 + n) * (2 * K) + sel * K + k0;
      short* dst = sel ? Wl : Wh;
#pragma unroll
      for (int j = 0; j < 4; ++j) {
        s8v v = *(const s8v*)(wp + j * 8);
        *(s4v*)&dst[n * 36 + j * 8] = __builtin_shufflevector(v, v, 0, 1, 2, 3);
        *(s4v*)&dst[n * 36 + j * 8 + 4] = __builtin_shufflevector(v, v, 4, 5, 6, 7);
      }
    } else {
      const float* W = (const float*)Wp + (size_t)z * Wbs;
      const int kr = t >> 3, c0 = (t & 7) * 16;
      const float* wp = W + (size_t)(k0 + kr) * N + n0 + c0;
      float x[16];
#pragma unroll
      for (int j = 0; j < 4; ++j) *(f4v*)&x[j * 4] = *(const f4v*)(wp + j * 4);
#pragma unroll
      for (int j = 0; j < 16; ++j) {
        short hh, ll; split2(x[j], hh, ll);
        Wh[(c0 + j) * 36 + kr] = hh;
        Wl[(c0 + j) * 36 + kr] = ll;
      }
    }
    __syncthreads();
    s8v whf[4], wlf[4];
#pragma unroll
    for (int ni = 0; ni < 4; ++ni) {
      whf[ni] = ldfrag(&Wh[(wn * 64 + ni * 16 + lr) * 36 + 4 * lg]);
      wlf[ni] = ldfrag(&Wl[(wn * 64 + ni * 16 + lr) * 36 + 4 * lg]);
    }
#pragma unroll
    for (int mi = 0; mi < 2; ++mi) {
      s8v ah = ldfrag(&Ah[(wm * 32 + mi * 16 + lr) * 36 + 4 * lg]);
      s8v al = ldfrag(&Al[(wm * 32 + mi * 16 + lr) * 36 + 4 * lg]);
#pragma unroll
      for (int ni = 0; ni < 4; ++ni) {
        acc[mi][ni] = __builtin_amdgcn_mfma_f32_16x16x32_bf16(ah, whf[ni], acc[mi][ni], 0, 0, 0);
        acc[mi][ni] = __builtin_amdgcn_mfma_f32_16x16x32_bf16(al, whf[ni], acc[mi][ni], 0, 0, 0);
        acc[mi][ni] = __builtin_amdgcn_mfma_f32_16x16x32_bf16(ah, wlf[ni], acc[mi][ni], 0, 0, 0);
      }
    }
    __syncthreads();
  }
  float* Cf = (float*)Cv + (size_t)z * Cbs;
  unsigned short* Ch = (unsigned short*)Cv + (size_t)z * Cbs;
#pragma unroll
  for (int mi = 0; mi < 2; ++mi) {
#pragma unroll
    for (int i = 0; i < 4; ++i) {
      int row = m0 + wm * 32 + mi * 16 + 4 * lg + i;
      if (row >= M) continue;
#pragma unroll
      for (int ni = 0; ni < 4; ++ni) {
        int col = n0 + wn * 64 + ni * 16 + lr;
        float v = acc[mi][ni][i] + (bias ? bias[col] : 0.f);
        if (RELU) v = fmaxf(v, 0.f);
        if (OUT == 0) Cf[(size_t)row * ldc + col] = v;
        else Ch[(size_t)row * ldc + col] = f2bf(v);
      }
    }
  }
}

// ---------------- fp32 GEMM (cls head only) ----------------
__global__ __launch_bounds__(256) void gemm32_kernel(
    const float* __restrict__ A, const float* __restrict__ W,
    const float* __restrict__ bias, float* __restrict__ C,
    int M, int N, int K) {
  __shared__ float As[16][65];
  __shared__ float Ws[16][65];
  const int n0 = blockIdx.x * 64, m0 = blockIdx.y * 64;
  const int t = threadIdx.x;
  const int tm = t >> 4, tn = t & 15;
  float acc[4][4] = {};
  for (int k0 = 0; k0 < K; k0 += 16) {
#pragma unroll
    for (int l = 0; l < 4; ++l) {
      int idx = t + l * 256;
      int am = idx >> 4, ak = idx & 15;
      int gm = m0 + am, gk = k0 + ak;
      As[ak][am] = (gm < M) ? A[(size_t)gm * K + gk] : 0.f;
      int wk = idx >> 6, wn = idx & 63;
      int gn = n0 + wn, gk2 = k0 + wk;
      Ws[wk][wn] = (gn < N) ? W[(size_t)gk2 * N + gn] : 0.f;
    }
    __syncthreads();
#pragma unroll
    for (int kk = 0; kk < 16; ++kk) {
      float a[4], b[4];
#pragma unroll
      for (int i = 0; i < 4; ++i) a[i] = As[kk][tm * 4 + i];
#pragma unroll
      for (int j = 0; j < 4; ++j) b[j] = Ws[kk][tn * 4 + j];
#pragma unroll
      for (int i = 0; i < 4; ++i)
#pragma unroll
        for (int j = 0; j < 4; ++j) acc[i][j] += a[i] * b[j];
    }
    __syncthreads();
  }
#pragma unroll
  for (int i = 0; i < 4; ++i) {
    int gm = m0 + tm * 4 + i;
    if (gm >= M) continue;
#pragma unroll
    for (int j = 0; j < 4; ++j) {
      int gn = n0 + tn * 4 + j;
      if (gn >= N) continue;
      C[(size_t)gm * N + gn] = acc[i][j] + bias[gn];
    }
  }
}

// ---------------- fused residual + layernorm ----------------
template <bool RES>
__global__ __launch_bounds__(256) void ln_kernel(const float* __restrict__ x,
                                                 const float* __restrict__ r,
                                                 const float* __restrict__ s,
                                                 const float* __restrict__ b,
                                                 float* __restrict__ out) {
  __shared__ float red[256];
  size_t row = blockIdx.x;
  int t = threadIdx.x;
  float v = x[row * D_ + t];
  if (RES) v += r[row * D_ + t];
  float mean = block_sum(v, red) * (1.f / D_);
  float c = v - mean;
  float var = block_sum(c * c, red) * (1.f / D_);
  out[row * D_ + t] = c * rsqrtf(var + 1e-5f) * s[t] + b[t];
}

// ---------------- flash attention v2 ----------------
// grid (64 = b*8+h, 4 q-tiles), 256 thr: r = t&31 (q-row), c8 = t>>5 (k-slice).
// K/V tiles 128x32 in LDS fp32 (converted at stage if KVBF16). Bias = packed bits.
template <bool BIAS, bool KVBF16>
__global__ __launch_bounds__(256) void fattn_kernel(
    const float* __restrict__ qb, int ldq,
    const void* __restrict__ kbv, int ldk,
    const void* __restrict__ vbv, int ldv,
    const unsigned int* __restrict__ bits,
    float* __restrict__ out, int P, int Pw) {
  __shared__ float smem[2 * KT_ * 36];   // K,V tiles; reused for final combine
  __shared__ float red[256];
  __shared__ float lsave[QT_];
  __shared__ unsigned int bb[QT_ * 4];
  float* Kt = smem;
  float* Vt = smem + KT_ * 36;
  const int b = blockIdx.x >> 3, h = blockIdx.x & 7;
  const int q0 = blockIdx.y * QT_;
  const int t = threadIdx.x;
  const int r = t & 31, c8 = t >> 5;
  const int qrow = q0 + r;
  const int qcl = (qrow < Q_) ? qrow : 0;
  float4 qreg[8];
  {
    const float4* qp = reinterpret_cast<const float4*>(qb + (size_t)(b * Q_ + qcl) * ldq + h * HD_);
#pragma unroll
    for (int e = 0; e < 8; ++e) qreg[e] = qp[e];
  }
  float m = -3.0e38f, l = 0.f;
  float O[32];
#pragma unroll
  for (int e = 0; e < 32; ++e) O[e] = 0.f;
  const float scale = 0.17677669529663687f;

  for (int k0 = 0; k0 < P; k0 += KT_) {
    // ---- stage K,V tiles ----
    if (KVBF16) {
      const unsigned short* kb = (const unsigned short*)kbv;
      const unsigned short* vb = (const unsigned short*)vbv;
#pragma unroll
      for (int i = 0; i < 2; ++i) {
        int cid = t + i * 256;             // 0..511
        int row = cid >> 2, c = (cid & 3) * 8;
        int gk = k0 + row;
        float kx[8], vx[8];
        if (gk < P) {
          s8v kv8 = *(const s8v*)(kb + (size_t)(b * P + gk) * ldk + h * HD_ + c);
          s8v vv8 = *(const s8v*)(vb + (size_t)(b * P + gk) * ldv + h * HD_ + c);
#pragma unroll
          for (int e = 0; e < 8; ++e) { kx[e] = bf2f((unsigned short)kv8[e]); vx[e] = bf2f((unsigned short)vv8[e]); }
        } else {
#pragma unroll
          for (int e = 0; e < 8; ++e) { kx[e] = 0.f; vx[e] = 0.f; }
        }
        *(f4v*)&Kt[row * 36 + c] = *(f4v*)&kx[0];
        *(f4v*)&Kt[row * 36 + c + 4] = *(f4v*)&kx[4];
        *(f4v*)&Vt[row * 36 + c] = *(f4v*)&vx[0];
        *(f4v*)&Vt[row * 36 + c + 4] = *(f4v*)&vx[4];
      }
    } else {
      const float* kb = (const float*)kbv;
      const float* vb = (const float*)vbv;
#pragma unroll
      for (int i = 0; i < 4; ++i) {
        int f = t + i * 256;
        int row = f >> 3, c4 = (f & 7) * 4;
        int gk = k0 + row;
        float4 kvv = make_float4(0.f, 0.f, 0.f, 0.f);
        float4 vvv = kvv;
        if (gk < P) {
          kvv = *reinterpret_cast<const float4*>(kb + (size_t)(b * P + gk) * ldk + h * HD_ + c4);
          vvv = *reinterpret_cast<const float4*>(vb + (size_t)(b * P + gk) * ldv + h * HD_ + c4);
        }
        *reinterpret_cast<float4*>(&Kt[row * 36 + c4]) = kvv;
        *reinterpret_cast<float4*>(&Vt[row * 36 + c4]) = vvv;
      }
    }
    if (BIAS && t < QT_ * 4) {
      int r2 = t >> 2, w = t & 3;
      int gr = q0 + r2, wi = (k0 >> 5) + w;
      bb[t] = (gr < Q_ && wi < Pw) ? bits[(size_t)(b * Q_ + gr) * Pw + wi] : 0u;
    }
    __syncthreads();
    // ---- scores: 16 keys per thread ----
    float p[16];
    float pmax = -3.0e38f;
#pragma unroll
    for (int j = 0; j < 16; ++j) {
      int kk = c8 * 16 + j;
      int gkk = k0 + kk;
      const float4* kp = reinterpret_cast<const float4*>(&Kt[kk * 36]);
      float s = 0.f;
#pragma unroll
      for (int e = 0; e < 8; ++e) {
        float4 kv4 = kp[e];
        s += qreg[e].x * kv4.x + qreg[e].y * kv4.y + qreg[e].z * kv4.z + qreg[e].w * kv4.w;
      }
      s *= scale;
      if (BIAS) {
        unsigned int word = bb[r * 4 + (kk >> 5)];
        if ((word >> (kk & 31)) & 1u) s += -1e9f;
      }
      if (gkk >= P) s = -3.0e38f;
      p[j] = s;
      pmax = fmaxf(pmax, s);
    }
    // ---- row max across 8 k-slices ----
    red[t] = pmax;
    __syncthreads();
#pragma unroll
    for (int s = 4; s > 0; s >>= 1) {
      if (c8 < s) red[t] = fmaxf(red[t], red[t + (s << 5)]);
      __syncthreads();
    }
    float mnew = fmaxf(m, red[r]);
    float corr = __expf(m - mnew);
    m = mnew;
    float lsum = 0.f;
#pragma unroll
    for (int j = 0; j < 16; ++j) {
      p[j] = __expf(p[j] - mnew);
      lsum += p[j];
    }
    l = l * corr + lsum;
#pragma unroll
    for (int e = 0; e < 32; ++e) O[e] *= corr;
    // ---- PV ----
#pragma unroll
    for (int j = 0; j < 16; ++j) {
      int kk = c8 * 16 + j;
      const float4* vp = reinterpret_cast<const float4*>(&Vt[kk * 36]);
      float pj = p[j];
#pragma unroll
      for (int e = 0; e < 8; ++e) {
        float4 vv = vp[e];
        O[e * 4 + 0] += pj * vv.x;
        O[e * 4 + 1] += pj * vv.y;
        O[e * 4 + 2] += pj * vv.z;
        O[e * 4 + 3] += pj * vv.w;
      }
    }
    __syncthreads();
  }
  // ---- final combine across the 8 k-slices ----
  red[t] = l;
  __syncthreads();
#pragma unroll
  for (int s = 4; s > 0; s >>= 1) {
    if (c8 < s) red[t] += red[t + (s << 5)];
    __syncthreads();
  }
  if (t < QT_) lsave[t] = red[t];
  float* sc = smem;                      // 256*33 = 8448 <= 9216 floats
#pragma unroll
  for (int e = 0; e < 32; ++e) sc[t * 33 + e] = O[e];
  __syncthreads();
  for (int o = t; o < QT_ * 32; o += 256) {
    int ro = o >> 5, eo = o & 31;
    if (q0 + ro < Q_) {
      float sacc = 0.f;
#pragma unroll
      for (int c = 0; c < 8; ++c) sacc += sc[(c * 32 + ro) * 33 + eo];
      out[(size_t)(b * Q_ + q0 + ro) * D_ + h * HD_ + eo] = sacc / lsave[ro];
    }
  }
}

// ---------------- attention-bias from prev mask (packed bits) ----------------
__global__ __launch_bounds__(256) void maskbias_kernel(
    const float* __restrict__ prev,
    unsigned int* __restrict__ bias,    // [B*Q][Pw] packed, bit=1 -> masked
    int oh) {
  __shared__ float pm[HM_ * HM_];
  __shared__ float rbuf[PMAX_];
  __shared__ float red[256];
  __shared__ unsigned int bw[128];
  const int row = blockIdx.x;
  const int t = threadIdx.x;
  const float* src = prev + (size_t)row * (HM_ * HM_);
  for (int i = t; i < HM_ * HM_; i += 256) pm[i] = src[i];
  __syncthreads();
  const int ratio = HM_ / oh;
  const int taps = 2 * ratio;
  const float invr = 1.f / (float)ratio;
  const int P = oh * oh;
  const int Pw = (P + 31) >> 5;
  float nign = 0.f;
  for (int p = t; p < P; p += 256) {
    int oy = p / oh, ox = p - oy * oh;
    float sy = (oy + 0.5f) * ratio - 0.5f;
    float sx = (ox + 0.5f) * ratio - 0.5f;
    int y0 = (int)floorf(sy - ratio) + 1;
    int x0 = (int)floorf(sx - ratio) + 1;
    float wxs = 0.f;
    for (int si = 0; si < taps; ++si) {
      int x = x0 + si;
      if (x < 0 || x >= HM_) continue;
      wxs += 1.f - fabsf(sx - x) * invr;
    }
    float acc = 0.f, wys = 0.f;
    for (int ti = 0; ti < taps; ++ti) {
      int y = y0 + ti;
      if (y < 0 || y >= HM_) continue;
      float wy = 1.f - fabsf(sy - y) * invr;
      wys += wy;
      float ra = 0.f;
      const float* pr = pm + y * HM_;
      for (int si = 0; si < taps; ++si) {
        int x = x0 + si;
        if (x < 0 || x >= HM_) continue;
        float wx = 1.f - fabsf(sx - x) * invr;
        ra += wx * pr[x];
      }
      acc += wy * ra;
    }
    float rv = acc / (wys * wxs);
    rbuf[p] = rv;
    if (!(rv < 0.f)) nign += 1.f;
  }
  float tot = block_sum(nign, red);
  bool fully = (tot == 0.f);
  for (int w = t; w < Pw; w += 256) bw[w] = 0u;
  __syncthreads();
  if (!fully) {
    for (int p = t; p < P; p += 256) {
      if (rbuf[p] < 0.f) atomicOr(&bw[p >> 5], 1u << (p & 31));
    }
  }
  __syncthreads();
  unsigned int* dst = bias + (size_t)row * Pw;
  for (int w = t; w < Pw; w += 256) dst[w] = bw[w];
}

// ---------------- host dispatch ----------------
static inline void mg(hipStream_t st, int amode, int wmode, bool relu, int outmode,
                      const void* A, const void* W, const float* bias, void* C,
                      int M, int N, int K, int Z,
                      long long Abs, long long Wbs, long long Cbs, int ldc) {
  dim3 g(N / 128, (M + 63) / 64, Z);
  if (amode == 1)
    mgemm_kernel<1, 0, false, 1><<<g, 256, 0, st>>>(A, W, bias, C, M, N, K, Abs, Wbs, Cbs, ldc);
  else if (wmode == 1)
    mgemm_kernel<0, 1, false, 0><<<g, 256, 0, st>>>(A, W, bias, C, M, N, K, Abs, Wbs, Cbs, ldc);
  else if (relu)
    mgemm_kernel<0, 0, true, 0><<<g, 256, 0, st>>>(A, W, bias, C, M, N, K, Abs, Wbs, Cbs, ldc);
  else
    mgemm_kernel<0, 0, false, 0><<<g, 256, 0, st>>>(A, W, bias, C, M, N, K, Abs, Wbs, Cbs, ldc);
}

extern "C" void kernel_launch(void* const* d_in, const int* in_sizes, int n_in,
                              void* d_out, int out_size, void* d_ws, size_t ws_size,
                              hipStream_t stream) {
  const float* mask_features = (const float*)d_in[0];
  const float* mem[3] = {(const float*)d_in[1], (const float*)d_in[2], (const float*)d_in[3]};
  const float* qf = (const float*)d_in[4];
  const float* qe = (const float*)d_in[5];
  const float* ca_wqkv = (const float*)d_in[6];
  const float* ca_bqkv = (const float*)d_in[7];
  const float* ca_wo = (const float*)d_in[8];
  const float* ca_bo = (const float*)d_in[9];
  const float* ca_ln_s = (const float*)d_in[10];
  const float* ca_ln_b = (const float*)d_in[11];
  const float* sa_wqkv = (const float*)d_in[12];
  const float* sa_bqkv = (const float*)d_in[13];
  const float* sa_wo = (const float*)d_in[14];
  const float* sa_bo = (const float*)d_in[15];
  const float* sa_ln_s = (const float*)d_in[16];
  const float* sa_ln_b = (const float*)d_in[17];
  const float* ffn_w1 = (const float*)d_in[18];
  const float* ffn_b1 = (const float*)d_in[19];
  const float* ffn_w2 = (const float*)d_in[20];
  const float* ffn_b2 = (const float*)d_in[21];
  const float* ffn_ln_s = (const float*)d_in[22];
  const float* ffn_ln_b = (const float*)d_in[23];
  const float* dec_ln_s = (const float*)d_in[24];
  const float* dec_ln_b = (const float*)d_in[25];
  const float* me_w1 = (const float*)d_in[26];
  const float* me_b1 = (const float*)d_in[27];
  const float* me_w2 = (const float*)d_in[28];
  const float* me_b2 = (const float*)d_in[29];
  const float* me_w3 = (const float*)d_in[30];
  const float* me_b3 = (const float*)d_in[31];
  const float* cls_w = (const float*)d_in[32];
  const float* cls_b = (const float*)d_in[33];

  float* out_logits = (float*)d_out;
  float* out_mask = (float*)d_out + (size_t)800 * C_;

  float* fws = (float*)d_ws;
  float* q      = fws; fws += (size_t)800 * D_;
  float* qh     = fws; fws += (size_t)800 * D_;
  float* attn_o = fws; fws += (size_t)800 * D_;
  float* tmp    = fws; fws += (size_t)800 * D_;
  float* nq     = fws; fws += (size_t)800 * D_;
  float* me1    = fws; fws += (size_t)800 * D_;
  float* me2    = fws; fws += (size_t)800 * D_;
  float* me3    = fws; fws += (size_t)800 * D_;
  float* kvbuf  = fws; fws += (size_t)B_ * PMAX_ * 256;    // bf16 [B][P][512]
  float* qkvbuf = fws; fws += (size_t)800 * 768;
  float* biasb  = fws; fws += (size_t)800 * 128;           // packed bits [800][Pw<=98]
  float* ffnh   = fws; fws += (size_t)B_ * Q_ * F_;

  unsigned short* kvb = (unsigned short*)kvbuf;
  unsigned int* biasbits = (unsigned int*)biasb;

  short* sws = (short*)fws;
  short* W2ca  = sws; sws += (size_t)27 * 256 * 512;
  short* W2sa  = sws; sws += (size_t)27 * 256 * 512;
  short* W2cao = sws; sws += (size_t)9 * 256 * 512;
  short* W2sao = sws; sws += (size_t)9 * 256 * 512;
  short* W2f1  = sws; sws += (size_t)9 * 2048 * 512;
  short* W2f2  = sws; sws += (size_t)9 * 256 * 4096;
  short* W2me  = sws; sws += (size_t)3 * 256 * 512;
  short* mem2s = sws; sws += (size_t)B_ * 3136 * 512;
  short* mem1s = sws; sws += (size_t)B_ * 784 * 512;
  short* mem0s = sws; sws += (size_t)B_ * 196 * 512;
  short* memsp[3] = {mem0s, mem1s, mem2s};

  tsplit_kernel<<<dim3(8, 8, 27), 256, 0, stream>>>(ca_wqkv, W2ca, 256, 256, 65536, 131072);
  tsplit_kernel<<<dim3(8, 8, 27), 256, 0, stream>>>(sa_wqkv, W2sa, 256, 256, 65536, 131072);
  tsplit_kernel<<<dim3(8, 8, 9), 256, 0, stream>>>(ca_wo, W2cao, 256, 256, 65536, 131072);
  tsplit_kernel<<<dim3(8, 8, 9), 256, 0, stream>>>(sa_wo, W2sao, 256, 256, 65536, 131072);
  tsplit_kernel<<<dim3(64, 8, 9), 256, 0, stream>>>(ffn_w1, W2f1, 256, 2048, 524288, 1048576);
  tsplit_kernel<<<dim3(8, 64, 9), 256, 0, stream>>>(ffn_w2, W2f2, 2048, 256, 524288, 1048576);
  tsplit_kernel<<<dim3(8, 8, 1), 256, 0, stream>>>(me_w1, W2me, 256, 256, 0, 0);
  tsplit_kernel<<<dim3(8, 8, 1), 256, 0, stream>>>(me_w2, W2me + 131072, 256, 256, 0, 0);
  tsplit_kernel<<<dim3(8, 8, 1), 256, 0, stream>>>(me_w3, W2me + 262144, 256, 256, 0, 0);
  tsplit_kernel<<<dim3(7, 8, 8), 256, 0, stream>>>(mem[0], mem0s, 256, 196, 256 * 196, 196 * 512);
  tsplit_kernel<<<dim3(25, 8, 8), 256, 0, stream>>>(mem[1], mem1s, 256, 784, 256 * 784, 784 * 512);
  tsplit_kernel<<<dim3(98, 8, 8), 256, 0, stream>>>(mem[2], mem2s, 256, 3136, 256 * 3136, 3136 * 512);

  initq_kernel<<<800, 256, 0, stream>>>(qf, qe, q);

  const int Ps[3] = {196, 784, 3136};
  const int ohs[3] = {14, 28, 56};
  const dim3 ag(64, 4);      // (b*8+h, q-tiles of 32)
  for (int i = 0; i < L_; ++i) {
    const int mi = i % 3, P = Ps[mi], oh = ohs[mi];
    const int Pw = (P + 31) >> 5;
    if (i > 0) maskbias_kernel<<<800, 256, 0, stream>>>(out_mask, biasbits, oh);
    // ---- cross-attention ----
    mg(stream, 0, 0, false, 0, q, W2ca + (size_t)(i * 3) * 131072, ca_bqkv + i * 768, qh,
       800, 256, 256, 1, 0, 0, 0, 256);
    mg(stream, 1, 0, false, 1, memsp[mi], W2ca + (size_t)(i * 3 + 1) * 131072,
       ca_bqkv + i * 768 + 256, kvb,
       P, 512, 256, B_, (long long)P * 512, 0, (long long)P * 512, 512);
    if (i > 0)
      fattn_kernel<true, true><<<ag, 256, 0, stream>>>(qh, 256, kvb, 512, kvb + 256, 512,
                                                       biasbits, attn_o, P, Pw);
    else
      fattn_kernel<false, true><<<ag, 256, 0, stream>>>(qh, 256, kvb, 512, kvb + 256, 512,
                                                        nullptr, attn_o, P, Pw);
    mg(stream, 0, 0, false, 0, attn_o, W2cao + (size_t)i * 131072, ca_bo + i * 256, tmp,
       800, 256, 256, 1, 0, 0, 0, 256);
    ln_kernel<true><<<800, 256, 0, stream>>>(q, tmp, ca_ln_s + i * 256, ca_ln_b + i * 256, q);
    // ---- self-attention ----
    mg(stream, 0, 0, false, 0, q, W2sa + (size_t)(i * 3) * 131072, sa_bqkv + i * 768, qkvbuf,
       800, 768, 256, 1, 0, 0, 0, 768);
    fattn_kernel<false, false><<<ag, 256, 0, stream>>>(qkvbuf, 768, qkvbuf + 256, 768,
                                                       qkvbuf + 512, 768, nullptr, attn_o, 100, 4);
    mg(stream, 0, 0, false, 0, attn_o, W2sao + (size_t)i * 131072, sa_bo + i * 256, tmp,
       800, 256, 256, 1, 0, 0, 0, 256);
    ln_kernel<true><<<800, 256, 0, stream>>>(q, tmp, sa_ln_s + i * 256, sa_ln_b + i * 256, q);
    // ---- FFN ----
    mg(stream, 0, 0, true, 0, q, W2f1 + (size_t)i * 1048576, ffn_b1 + i * 2048, ffnh,
       800, 2048, 256, 1, 0, 0, 0, 2048);
    mg(stream, 0, 0, false, 0, ffnh, W2f2 + (size_t)i * 1048576, ffn_b2 + i * 256, tmp,
       800, 256, 2048, 1, 0, 0, 0, 256);
    ln_kernel<true><<<800, 256, 0, stream>>>(q, tmp, ffn_ln_s + i * 256, ffn_ln_b + i * 256, q);
    // ---- mask head ----
    ln_kernel<false><<<800, 256, 0, stream>>>(q, nullptr, dec_ln_s, dec_ln_b, nq);
    mg(stream, 0, 0, true, 0, nq, W2me, me_b1, me1, 800, 256, 256, 1, 0, 0, 0, 256);
    mg(stream, 0, 0, true, 0, me1, W2me + 131072, me_b2, me2, 800, 256, 256, 1, 0, 0, 0, 256);
    mg(stream, 0, 0, false, 0, me2, W2me + 262144, me_b3, me3, 800, 256, 256, 1, 0, 0, 0, 256);
    mg(stream, 0, 1, false, 0, me3, mask_features, nullptr, out_mask,
       100, 12544, 256, B_, (long long)100 * 256, (long long)256 * 12544,
       (long long)100 * 12544, 12544);
  }
  gemm32_kernel<<<dim3(3, 13, 1), 256, 0, stream>>>(nq, cls_w, cls_b, out_logits, 800, C_, 256);
}

// Round 5
// 4035.500 us; speedup vs baseline: 1.0426x; 1.0426x over previous
//
#include <hip/hip_runtime.h>
#include <cmath>

#define B_ 8
#define Q_ 100
#define D_ 256
#define H_ 8
#define HD_ 32
#define L_ 9
#define F_ 2048
#define C_ 151
#define HM_ 112
#define PMAX_ 3136
#define QT_ 32
#define KT_ 128
#define RECSZ 1088   // 32 m + 32 l + 32*32 O

#define KBLK4 1

typedef __attribute__((ext_vector_type(4))) short s4v;
typedef __attribute__((ext_vector_type(8))) short s8v;
typedef __attribute__((ext_vector_type(4))) float f4v;

__device__ __forceinline__ unsigned short f2bf(float x) {
  unsigned int u = __float_as_uint(x);
  return (unsigned short)((u + 0x7fffu + ((u >> 16) & 1u)) >> 16);
}
__device__ __forceinline__ float bf2f(unsigned short h) {
  return __uint_as_float(((unsigned int)h) << 16);
}
__device__ __forceinline__ void split2(float x, short& h, short& l) {
  unsigned short hb = f2bf(x);
  float r = x - bf2f(hb);
  h = (short)hb;
  l = (short)f2bf(r);
}

// ---------------- block reductions (256 threads) ----------------
__device__ __forceinline__ float block_sum(float v, float* red) {
  int t = threadIdx.x;
  red[t] = v; __syncthreads();
  for (int s = 128; s > 0; s >>= 1) {
    if (t < s) red[t] += red[t + s];
    __syncthreads();
  }
  float r = red[0]; __syncthreads();
  return r;
}

// ---------------- init q ----------------
__global__ __launch_bounds__(256) void initq_kernel(const float* __restrict__ qf,
                                                    const float* __restrict__ qe,
                                                    float* __restrict__ q) {
  int idx = blockIdx.x * 256 + threadIdx.x;
  int qd = idx % (Q_ * D_);
  q[idx] = qf[qd] + qe[qd];
}

// ---------------- transpose-split: fp32 [K][N] -> bf16 [N][2K] ----------------
__global__ __launch_bounds__(256) void tsplit_kernel(
    const float* __restrict__ in, short* __restrict__ out,
    int K, int N, long long ibs, long long obs) {
  __shared__ float tile[32][33];
  const int z = blockIdx.z;
  const int nb = blockIdx.x * 32, kb = blockIdx.y * 32;
  const float* I = in + (size_t)z * ibs;
  short* O = out + (size_t)z * obs;
  const int t = threadIdx.x;
  {
    const int r = t >> 3, c = (t & 7) * 4;
    const int gk = kb + r;
#pragma unroll
    for (int j = 0; j < 4; ++j) {
      int gn = nb + c + j;
      tile[r][c + j] = (gk < K && gn < N) ? I[(size_t)gk * N + gn] : 0.f;
    }
  }
  __syncthreads();
  {
    const int nr = t >> 3, kc = (t & 7) * 4;
    const int gn = nb + nr;
    if (gn < N) {
#pragma unroll
      for (int j = 0; j < 4; ++j) {
        int gk = kb + kc + j;
        if (gk < K) {
          short h, l; split2(tile[kc + j][nr], h, l);
          O[(size_t)gn * 2 * K + gk] = h;
          O[(size_t)gn * 2 * K + K + gk] = l;
        }
      }
    }
  }
}

// ---------------- MFMA bf16x3 GEMM ----------------
__device__ __forceinline__ s8v ldfrag(const short* p) {
#if KBLK4
  s4v lo = *(const s4v*)p;
  s4v hi = *(const s4v*)(p + 16);
  return __builtin_shufflevector(lo, hi, 0, 1, 2, 3, 4, 5, 6, 7);
#else
  s4v lo = *(const s4v*)p;
  s4v hi = *(const s4v*)(p + 4);
  return __builtin_shufflevector(lo, hi, 0, 1, 2, 3, 4, 5, 6, 7);
#endif
}

// OUT: 0 = fp32 store, 1 = bf16 store
template <int AMODE, int WMODE, bool RELU, int OUT>
__global__ __launch_bounds__(256) void mgemm_kernel(
    const void* __restrict__ Ap, const void* __restrict__ Wp,
    const float* __restrict__ bias, void* __restrict__ Cv,
    int M, int N, int K,
    long long Abs, long long Wbs, long long Cbs, int ldc) {
  __shared__ short Ah[64 * 36], Al[64 * 36], Wh[128 * 36], Wl[128 * 36];
  const int z = blockIdx.z;
  const int n0 = blockIdx.x * 128, m0 = blockIdx.y * 64;
  const int t = threadIdx.x;
  const int lane = t & 63;
  const int wave = t >> 6;
  const int wm = wave >> 1, wn = wave & 1;
  const int lr = lane & 15, lg = lane >> 4;
  f4v acc[2][4];
#pragma unroll
  for (int i = 0; i < 2; ++i)
#pragma unroll
    for (int j = 0; j < 4; ++j) acc[i][j] = (f4v){0.f, 0.f, 0.f, 0.f};

  const int arow = t >> 2;

  for (int k0 = 0; k0 < K; k0 += 32) {
    if (AMODE == 0) {
      const float* A = (const float*)Ap + (size_t)z * Abs;
      const int kc = (t & 3) * 8;
      float x[8];
      if (m0 + arow < M) {
        const float* ap = A + (size_t)(m0 + arow) * K + k0 + kc;
        *(f4v*)&x[0] = *(const f4v*)ap;
        *(f4v*)&x[4] = *(const f4v*)(ap + 4);
      } else {
#pragma unroll
        for (int e = 0; e < 8; ++e) x[e] = 0.f;
      }
      s4v h0, h1, l0, l1;
#pragma unroll
      for (int e = 0; e < 4; ++e) { short hh, ll; split2(x[e], hh, ll); h0[e] = hh; l0[e] = ll; }
#pragma unroll
      for (int e = 0; e < 4; ++e) { short hh, ll; split2(x[4 + e], hh, ll); h1[e] = hh; l1[e] = ll; }
      *(s4v*)&Ah[arow * 36 + kc] = h0; *(s4v*)&Ah[arow * 36 + kc + 4] = h1;
      *(s4v*)&Al[arow * 36 + kc] = l0; *(s4v*)&Al[arow * 36 + kc + 4] = l1;
    } else {
      const short* A2 = (const short*)Ap + (size_t)z * Abs;
      const int c = t & 3, sel = c >> 1, ko = (c & 1) * 16;
      s8v v0 = {0, 0, 0, 0, 0, 0, 0, 0}, v1 = {0, 0, 0, 0, 0, 0, 0, 0};
      if (m0 + arow < M) {
        const short* ap = A2 + (size_t)(m0 + arow) * (2 * K) + sel * K + k0 + ko;
        v0 = *(const s8v*)ap;
        v1 = *(const s8v*)(ap + 8);
      }
      short* dst = sel ? Al : Ah;
      *(s4v*)&dst[arow * 36 + ko] = __builtin_shufflevector(v0, v0, 0, 1, 2, 3);
      *(s4v*)&dst[arow * 36 + ko + 4] = __builtin_shufflevector(v0, v0, 4, 5, 6, 7);
      *(s4v*)&dst[arow * 36 + ko + 8] = __builtin_shufflevector(v1, v1, 0, 1, 2, 3);
      *(s4v*)&dst[arow * 36 + ko + 12] = __builtin_shufflevector(v1, v1, 4, 5, 6, 7);
    }
    if (WMODE == 0) {
      const short* W2 = (const short*)Wp + (size_t)z * Wbs;
      const int n = t >> 1, sel = t & 1;
      const short* wp = W2 + (size_t)(n0 + n) * (2 * K) + sel * K + k0;
      short* dst = sel ? Wl : Wh;
#pragma unroll
      for (int j = 0; j < 4; ++j) {
        s8v v = *(const s8v*)(wp + j * 8);
        *(s4v*)&dst[n * 36 + j * 8] = __builtin_shufflevector(v, v, 0, 1, 2, 3);
        *(s4v*)&dst[n * 36 + j * 8 + 4] = __builtin_shufflevector(v, v, 4, 5, 6, 7);
      }
    } else {
      const float* W = (const float*)Wp + (size_t)z * Wbs;
      const int kr = t >> 3, c0 = (t & 7) * 16;
      const float* wp = W + (size_t)(k0 + kr) * N + n0 + c0;
      float x[16];
#pragma unroll
      for (int j = 0; j < 4; ++j) *(f4v*)&x[j * 4] = *(const f4v*)(wp + j * 4);
#pragma unroll
      for (int j = 0; j < 16; ++j) {
        short hh, ll; split2(x[j], hh, ll);
        Wh[(c0 + j) * 36 + kr] = hh;
        Wl[(c0 + j) * 36 + kr] = ll;
      }
    }
    __syncthreads();
    s8v whf[4], wlf[4];
#pragma unroll
    for (int ni = 0; ni < 4; ++ni) {
      whf[ni] = ldfrag(&Wh[(wn * 64 + ni * 16 + lr) * 36 + 4 * lg]);
      wlf[ni] = ldfrag(&Wl[(wn * 64 + ni * 16 + lr) * 36 + 4 * lg]);
    }
#pragma unroll
    for (int mi = 0; mi < 2; ++mi) {
      s8v ah = ldfrag(&Ah[(wm * 32 + mi * 16 + lr) * 36 + 4 * lg]);
      s8v al = ldfrag(&Al[(wm * 32 + mi * 16 + lr) * 36 + 4 * lg]);
#pragma unroll
      for (int ni = 0; ni < 4; ++ni) {
        acc[mi][ni] = __builtin_amdgcn_mfma_f32_16x16x32_bf16(ah, whf[ni], acc[mi][ni], 0, 0, 0);
        acc[mi][ni] = __builtin_amdgcn_mfma_f32_16x16x32_bf16(al, whf[ni], acc[mi][ni], 0, 0, 0);
        acc[mi][ni] = __builtin_amdgcn_mfma_f32_16x16x32_bf16(ah, wlf[ni], acc[mi][ni], 0, 0, 0);
      }
    }
    __syncthreads();
  }
  float* Cf = (float*)Cv + (size_t)z * Cbs;
  unsigned short* Ch = (unsigned short*)Cv + (size_t)z * Cbs;
#pragma unroll
  for (int mi = 0; mi < 2; ++mi) {
#pragma unroll
    for (int i = 0; i < 4; ++i) {
      int row = m0 + wm * 32 + mi * 16 + 4 * lg + i;
      if (row >= M) continue;
#pragma unroll
      for (int ni = 0; ni < 4; ++ni) {
        int col = n0 + wn * 64 + ni * 16 + lr;
        float v = acc[mi][ni][i] + (bias ? bias[col] : 0.f);
        if (RELU) v = fmaxf(v, 0.f);
        if (OUT == 0) Cf[(size_t)row * ldc + col] = v;
        else Ch[(size_t)row * ldc + col] = f2bf(v);
      }
    }
  }
}

// ---------------- fp32 GEMM (cls head only) ----------------
__global__ __launch_bounds__(256) void gemm32_kernel(
    const float* __restrict__ A, const float* __restrict__ W,
    const float* __restrict__ bias, float* __restrict__ C,
    int M, int N, int K) {
  __shared__ float As[16][65];
  __shared__ float Ws[16][65];
  const int n0 = blockIdx.x * 64, m0 = blockIdx.y * 64;
  const int t = threadIdx.x;
  const int tm = t >> 4, tn = t & 15;
  float acc[4][4] = {};
  for (int k0 = 0; k0 < K; k0 += 16) {
#pragma unroll
    for (int l = 0; l < 4; ++l) {
      int idx = t + l * 256;
      int am = idx >> 4, ak = idx & 15;
      int gm = m0 + am, gk = k0 + ak;
      As[ak][am] = (gm < M) ? A[(size_t)gm * K + gk] : 0.f;
      int wk = idx >> 6, wn = idx & 63;
      int gn = n0 + wn, gk2 = k0 + wk;
      Ws[wk][wn] = (gn < N) ? W[(size_t)gk2 * N + gn] : 0.f;
    }
    __syncthreads();
#pragma unroll
    for (int kk = 0; kk < 16; ++kk) {
      float a[4], b[4];
#pragma unroll
      for (int i = 0; i < 4; ++i) a[i] = As[kk][tm * 4 + i];
#pragma unroll
      for (int j = 0; j < 4; ++j) b[j] = Ws[kk][tn * 4 + j];
#pragma unroll
      for (int i = 0; i < 4; ++i)
#pragma unroll
        for (int j = 0; j < 4; ++j) acc[i][j] += a[i] * b[j];
    }
    __syncthreads();
  }
#pragma unroll
  for (int i = 0; i < 4; ++i) {
    int gm = m0 + tm * 4 + i;
    if (gm >= M) continue;
#pragma unroll
    for (int j = 0; j < 4; ++j) {
      int gn = n0 + tn * 4 + j;
      if (gn >= N) continue;
      C[(size_t)gm * N + gn] = acc[i][j] + bias[gn];
    }
  }
}

// ---------------- fused residual + layernorm ----------------
template <bool RES>
__global__ __launch_bounds__(256) void ln_kernel(const float* __restrict__ x,
                                                 const float* __restrict__ r,
                                                 const float* __restrict__ s,
                                                 const float* __restrict__ b,
                                                 float* __restrict__ out) {
  __shared__ float red[256];
  size_t row = blockIdx.x;
  int t = threadIdx.x;
  float v = x[row * D_ + t];
  if (RES) v += r[row * D_ + t];
  float mean = block_sum(v, red) * (1.f / D_);
  float c = v - mean;
  float var = block_sum(c * c, red) * (1.f / D_);
  out[row * D_ + t] = c * rsqrtf(var + 1e-5f) * s[t] + b[t];
}

// ---------------- flash attention v3 (split-K) ----------------
// grid (64 = b*8+h, q-tiles, S segments). 256 thr: r = t&31, c8 = t>>5.
// SPLIT: write unnormalized partial record [32 m][32 l][32x32 O] to part.
template <bool BIAS, bool KVBF16, bool SPLIT>
__global__ __launch_bounds__(256) void fattn_kernel(
    const float* __restrict__ qb, int ldq,
    const void* __restrict__ kbv, int ldk,
    const void* __restrict__ vbv, int ldv,
    const unsigned int* __restrict__ bits,
    float* __restrict__ outp, int P, int Pw, int tps, int S) {
  __shared__ float smem[2 * KT_ * 36];
  __shared__ float red[256];
  __shared__ float lsave[QT_];
  __shared__ unsigned int bb[QT_ * 4];
  float* Kt = smem;
  float* Vt = smem + KT_ * 36;
  const int b = blockIdx.x >> 3, h = blockIdx.x & 7;
  const int q0 = blockIdx.y * QT_;
  const int seg = blockIdx.z;
  const int kbeg = seg * tps * KT_;
  const int kend = min(P, kbeg + tps * KT_);
  const int t = threadIdx.x;
  const int r = t & 31, c8 = t >> 5;
  const int qrow = q0 + r;
  const int qcl = (qrow < Q_) ? qrow : 0;
  float4 qreg[8];
  {
    const float4* qp = reinterpret_cast<const float4*>(qb + (size_t)(b * Q_ + qcl) * ldq + h * HD_);
#pragma unroll
    for (int e = 0; e < 8; ++e) qreg[e] = qp[e];
  }
  float m = -3.0e38f, l = 0.f;
  float O[32];
#pragma unroll
  for (int e = 0; e < 32; ++e) O[e] = 0.f;
  const float scale = 0.17677669529663687f;

  for (int k0 = kbeg; k0 < kend; k0 += KT_) {
    if (KVBF16) {
      const unsigned short* kb = (const unsigned short*)kbv;
      const unsigned short* vb = (const unsigned short*)vbv;
#pragma unroll
      for (int i = 0; i < 2; ++i) {
        int cid = t + i * 256;
        int row = cid >> 2, c = (cid & 3) * 8;
        int gk = k0 + row;
        float kx[8], vx[8];
        if (gk < kend) {
          s8v kv8 = *(const s8v*)(kb + (size_t)(b * P + gk) * ldk + h * HD_ + c);
          s8v vv8 = *(const s8v*)(vb + (size_t)(b * P + gk) * ldv + h * HD_ + c);
#pragma unroll
          for (int e = 0; e < 8; ++e) { kx[e] = bf2f((unsigned short)kv8[e]); vx[e] = bf2f((unsigned short)vv8[e]); }
        } else {
#pragma unroll
          for (int e = 0; e < 8; ++e) { kx[e] = 0.f; vx[e] = 0.f; }
        }
        *(f4v*)&Kt[row * 36 + c] = *(f4v*)&kx[0];
        *(f4v*)&Kt[row * 36 + c + 4] = *(f4v*)&kx[4];
        *(f4v*)&Vt[row * 36 + c] = *(f4v*)&vx[0];
        *(f4v*)&Vt[row * 36 + c + 4] = *(f4v*)&vx[4];
      }
    } else {
      const float* kb = (const float*)kbv;
      const float* vb = (const float*)vbv;
#pragma unroll
      for (int i = 0; i < 4; ++i) {
        int f = t + i * 256;
        int row = f >> 3, c4 = (f & 7) * 4;
        int gk = k0 + row;
        float4 kvv = make_float4(0.f, 0.f, 0.f, 0.f);
        float4 vvv = kvv;
        if (gk < kend) {
          kvv = *reinterpret_cast<const float4*>(kb + (size_t)(b * P + gk) * ldk + h * HD_ + c4);
          vvv = *reinterpret_cast<const float4*>(vb + (size_t)(b * P + gk) * ldv + h * HD_ + c4);
        }
        *reinterpret_cast<float4*>(&Kt[row * 36 + c4]) = kvv;
        *reinterpret_cast<float4*>(&Vt[row * 36 + c4]) = vvv;
      }
    }
    if (BIAS && t < QT_ * 4) {
      int r2 = t >> 2, w = t & 3;
      int gr = q0 + r2, wi = (k0 >> 5) + w;
      bb[t] = (gr < Q_ && wi < Pw) ? bits[(size_t)(b * Q_ + gr) * Pw + wi] : 0u;
    }
    __syncthreads();
    float p[16];
    float pmax = -3.0e38f;
#pragma unroll
    for (int j = 0; j < 16; ++j) {
      int kk = c8 * 16 + j;
      int gkk = k0 + kk;
      const float4* kp = reinterpret_cast<const float4*>(&Kt[kk * 36]);
      float s = 0.f;
#pragma unroll
      for (int e = 0; e < 8; ++e) {
        float4 kv4 = kp[e];
        s += qreg[e].x * kv4.x + qreg[e].y * kv4.y + qreg[e].z * kv4.z + qreg[e].w * kv4.w;
      }
      s *= scale;
      if (BIAS) {
        unsigned int word = bb[r * 4 + (kk >> 5)];
        if ((word >> (kk & 31)) & 1u) s += -1e9f;
      }
      if (gkk >= kend) s = -3.0e38f;
      p[j] = s;
      pmax = fmaxf(pmax, s);
    }
    red[t] = pmax;
    __syncthreads();
#pragma unroll
    for (int s = 4; s > 0; s >>= 1) {
      if (c8 < s) red[t] = fmaxf(red[t], red[t + (s << 5)]);
      __syncthreads();
    }
    float mnew = fmaxf(m, red[r]);
    float corr = __expf(m - mnew);
    m = mnew;
    float lsum = 0.f;
#pragma unroll
    for (int j = 0; j < 16; ++j) {
      p[j] = __expf(p[j] - mnew);
      lsum += p[j];
    }
    l = l * corr + lsum;
#pragma unroll
    for (int e = 0; e < 32; ++e) O[e] *= corr;
#pragma unroll
    for (int j = 0; j < 16; ++j) {
      int kk = c8 * 16 + j;
      const float4* vp = reinterpret_cast<const float4*>(&Vt[kk * 36]);
      float pj = p[j];
#pragma unroll
      for (int e = 0; e < 8; ++e) {
        float4 vv = vp[e];
        O[e * 4 + 0] += pj * vv.x;
        O[e * 4 + 1] += pj * vv.y;
        O[e * 4 + 2] += pj * vv.z;
        O[e * 4 + 3] += pj * vv.w;
      }
    }
    __syncthreads();
  }
  // ---- combine l across the 8 k-slices ----
  red[t] = l;
  __syncthreads();
#pragma unroll
  for (int s = 4; s > 0; s >>= 1) {
    if (c8 < s) red[t] += red[t + (s << 5)];
    __syncthreads();
  }
  if (t < QT_) lsave[t] = red[t];
  float* part = SPLIT
      ? outp + ((size_t)((blockIdx.x * gridDim.y + blockIdx.y) * S + seg)) * RECSZ
      : nullptr;
  if (SPLIT && t < QT_) {
    part[t] = m;            // row t's m (thread t has r==t, and m is row-uniform)
    part[32 + t] = red[t];  // l_tot
  }
  float* sc = smem;
#pragma unroll
  for (int e = 0; e < 32; ++e) sc[t * 33 + e] = O[e];
  __syncthreads();
  for (int o = t; o < QT_ * 32; o += 256) {
    int ro = o >> 5, eo = o & 31;
    float sacc = 0.f;
#pragma unroll
    for (int c = 0; c < 8; ++c) sacc += sc[(c * 32 + ro) * 33 + eo];
    if (SPLIT) {
      part[64 + o] = sacc;
    } else if (q0 + ro < Q_) {
      outp[(size_t)(b * Q_ + q0 + ro) * D_ + h * HD_ + eo] = sacc / lsave[ro];
    }
  }
}

// ---------------- split-K combine: out[b,q,h,d] from S partial records ----------------
__global__ __launch_bounds__(256) void attncomb_kernel(
    const float* __restrict__ part, float* __restrict__ out, int S, int nqt) {
  const int row = blockIdx.x;               // b*Q + q
  const int b = row / Q_, qq = row % Q_;
  const int t = threadIdx.x;
  const int h = t >> 5, d = t & 31;
  const int qt = qq >> 5, r = qq & 31;
  const float* base = part + ((size_t)((b * 8 + h) * nqt + qt) * S) * RECSZ;
  float M = -3.0e38f;
  for (int s = 0; s < S; ++s) M = fmaxf(M, base[(size_t)s * RECSZ + r]);
  float lt = 0.f, Ov = 0.f;
  for (int s = 0; s < S; ++s) {
    const float* rec = base + (size_t)s * RECSZ;
    float w = __expf(rec[r] - M);
    lt += w * rec[32 + r];
    Ov += w * rec[64 + r * 32 + d];
  }
  out[(size_t)row * D_ + h * HD_ + d] = Ov / lt;
}

// ---------------- attention-bias from prev mask (packed bits) ----------------
__global__ __launch_bounds__(256) void maskbias_kernel(
    const float* __restrict__ prev,
    unsigned int* __restrict__ bias,
    int oh) {
  __shared__ float pm[HM_ * HM_];
  __shared__ float rbuf[PMAX_];
  __shared__ float red[256];
  __shared__ unsigned int bw[128];
  const int row = blockIdx.x;
  const int t = threadIdx.x;
  const float* src = prev + (size_t)row * (HM_ * HM_);
  for (int i = t; i < HM_ * HM_; i += 256) pm[i] = src[i];
  __syncthreads();
  const int ratio = HM_ / oh;
  const int taps = 2 * ratio;
  const float invr = 1.f / (float)ratio;
  const int P = oh * oh;
  const int Pw = (P + 31) >> 5;
  float nign = 0.f;
  for (int p = t; p < P; p += 256) {
    int oy = p / oh, ox = p - oy * oh;
    float sy = (oy + 0.5f) * ratio - 0.5f;
    float sx = (ox + 0.5f) * ratio - 0.5f;
    int y0 = (int)floorf(sy - ratio) + 1;
    int x0 = (int)floorf(sx - ratio) + 1;
    float wxs = 0.f;
    for (int si = 0; si < taps; ++si) {
      int x = x0 + si;
      if (x < 0 || x >= HM_) continue;
      wxs += 1.f - fabsf(sx - x) * invr;
    }
    float acc = 0.f, wys = 0.f;
    for (int ti = 0; ti < taps; ++ti) {
      int y = y0 + ti;
      if (y < 0 || y >= HM_) continue;
      float wy = 1.f - fabsf(sy - y) * invr;
      wys += wy;
      float ra = 0.f;
      const float* pr = pm + y * HM_;
      for (int si = 0; si < taps; ++si) {
        int x = x0 + si;
        if (x < 0 || x >= HM_) continue;
        float wx = 1.f - fabsf(sx - x) * invr;
        ra += wx * pr[x];
      }
      acc += wy * ra;
    }
    float rv = acc / (wys * wxs);
    rbuf[p] = rv;
    if (!(rv < 0.f)) nign += 1.f;
  }
  float tot = block_sum(nign, red);
  bool fully = (tot == 0.f);
  for (int w = t; w < Pw; w += 256) bw[w] = 0u;
  __syncthreads();
  if (!fully) {
    for (int p = t; p < P; p += 256) {
      if (rbuf[p] < 0.f) atomicOr(&bw[p >> 5], 1u << (p & 31));
    }
  }
  __syncthreads();
  unsigned int* dst = bias + (size_t)row * Pw;
  for (int w = t; w < Pw; w += 256) dst[w] = bw[w];
}

// ---------------- host dispatch ----------------
static inline void mg(hipStream_t st, int amode, int wmode, bool relu, int outmode,
                      const void* A, const void* W, const float* bias, void* C,
                      int M, int N, int K, int Z,
                      long long Abs, long long Wbs, long long Cbs, int ldc) {
  dim3 g(N / 128, (M + 63) / 64, Z);
  if (amode == 1)
    mgemm_kernel<1, 0, false, 1><<<g, 256, 0, st>>>(A, W, bias, C, M, N, K, Abs, Wbs, Cbs, ldc);
  else if (wmode == 1)
    mgemm_kernel<0, 1, false, 0><<<g, 256, 0, st>>>(A, W, bias, C, M, N, K, Abs, Wbs, Cbs, ldc);
  else if (relu)
    mgemm_kernel<0, 0, true, 0><<<g, 256, 0, st>>>(A, W, bias, C, M, N, K, Abs, Wbs, Cbs, ldc);
  else
    mgemm_kernel<0, 0, false, 0><<<g, 256, 0, st>>>(A, W, bias, C, M, N, K, Abs, Wbs, Cbs, ldc);
}

extern "C" void kernel_launch(void* const* d_in, const int* in_sizes, int n_in,
                              void* d_out, int out_size, void* d_ws, size_t ws_size,
                              hipStream_t stream) {
  const float* mask_features = (const float*)d_in[0];
  const float* mem[3] = {(const float*)d_in[1], (const float*)d_in[2], (const float*)d_in[3]};
  const float* qf = (const float*)d_in[4];
  const float* qe = (const float*)d_in[5];
  const float* ca_wqkv = (const float*)d_in[6];
  const float* ca_bqkv = (const float*)d_in[7];
  const float* ca_wo = (const float*)d_in[8];
  const float* ca_bo = (const float*)d_in[9];
  const float* ca_ln_s = (const float*)d_in[10];
  const float* ca_ln_b = (const float*)d_in[11];
  const float* sa_wqkv = (const float*)d_in[12];
  const float* sa_bqkv = (const float*)d_in[13];
  const float* sa_wo = (const float*)d_in[14];
  const float* sa_bo = (const float*)d_in[15];
  const float* sa_ln_s = (const float*)d_in[16];
  const float* sa_ln_b = (const float*)d_in[17];
  const float* ffn_w1 = (const float*)d_in[18];
  const float* ffn_b1 = (const float*)d_in[19];
  const float* ffn_w2 = (const float*)d_in[20];
  const float* ffn_b2 = (const float*)d_in[21];
  const float* ffn_ln_s = (const float*)d_in[22];
  const float* ffn_ln_b = (const float*)d_in[23];
  const float* dec_ln_s = (const float*)d_in[24];
  const float* dec_ln_b = (const float*)d_in[25];
  const float* me_w1 = (const float*)d_in[26];
  const float* me_b1 = (const float*)d_in[27];
  const float* me_w2 = (const float*)d_in[28];
  const float* me_b2 = (const float*)d_in[29];
  const float* me_w3 = (const float*)d_in[30];
  const float* me_b3 = (const float*)d_in[31];
  const float* cls_w = (const float*)d_in[32];
  const float* cls_b = (const float*)d_in[33];

  float* out_logits = (float*)d_out;
  float* out_mask = (float*)d_out + (size_t)800 * C_;

  float* fws = (float*)d_ws;
  float* q      = fws; fws += (size_t)800 * D_;
  float* qh     = fws; fws += (size_t)800 * D_;
  float* attn_o = fws; fws += (size_t)800 * D_;
  float* tmp    = fws; fws += (size_t)800 * D_;
  float* nq     = fws; fws += (size_t)800 * D_;
  float* me1    = fws; fws += (size_t)800 * D_;
  float* me2    = fws; fws += (size_t)800 * D_;
  float* me3    = fws; fws += (size_t)800 * D_;
  float* kvbuf  = fws; fws += (size_t)B_ * PMAX_ * 256;    // bf16 [B][P][512]
  float* qkvbuf = fws; fws += (size_t)800 * 768;
  float* biasb  = fws; fws += (size_t)800 * 128;
  float* ffnh   = fws; fws += (size_t)B_ * Q_ * F_;
  float* part   = fws; fws += (size_t)64 * 4 * 5 * RECSZ;  // split-K partials

  unsigned short* kvb = (unsigned short*)kvbuf;
  unsigned int* biasbits = (unsigned int*)biasb;

  short* sws = (short*)fws;
  short* W2ca  = sws; sws += (size_t)27 * 256 * 512;
  short* W2sa  = sws; sws += (size_t)27 * 256 * 512;
  short* W2cao = sws; sws += (size_t)9 * 256 * 512;
  short* W2sao = sws; sws += (size_t)9 * 256 * 512;
  short* W2f1  = sws; sws += (size_t)9 * 2048 * 512;
  short* W2f2  = sws; sws += (size_t)9 * 256 * 4096;
  short* W2me  = sws; sws += (size_t)3 * 256 * 512;
  short* mem2s = sws; sws += (size_t)B_ * 3136 * 512;
  short* mem1s = sws; sws += (size_t)B_ * 784 * 512;
  short* mem0s = sws; sws += (size_t)B_ * 196 * 512;
  short* memsp[3] = {mem0s, mem1s, mem2s};

  tsplit_kernel<<<dim3(8, 8, 27), 256, 0, stream>>>(ca_wqkv, W2ca, 256, 256, 65536, 131072);
  tsplit_kernel<<<dim3(8, 8, 27), 256, 0, stream>>>(sa_wqkv, W2sa, 256, 256, 65536, 131072);
  tsplit_kernel<<<dim3(8, 8, 9), 256, 0, stream>>>(ca_wo, W2cao, 256, 256, 65536, 131072);
  tsplit_kernel<<<dim3(8, 8, 9), 256, 0, stream>>>(sa_wo, W2sao, 256, 256, 65536, 131072);
  tsplit_kernel<<<dim3(64, 8, 9), 256, 0, stream>>>(ffn_w1, W2f1, 256, 2048, 524288, 1048576);
  tsplit_kernel<<<dim3(8, 64, 9), 256, 0, stream>>>(ffn_w2, W2f2, 2048, 256, 524288, 1048576);
  tsplit_kernel<<<dim3(8, 8, 1), 256, 0, stream>>>(me_w1, W2me, 256, 256, 0, 0);
  tsplit_kernel<<<dim3(8, 8, 1), 256, 0, stream>>>(me_w2, W2me + 131072, 256, 256, 0, 0);
  tsplit_kernel<<<dim3(8, 8, 1), 256, 0, stream>>>(me_w3, W2me + 262144, 256, 256, 0, 0);
  tsplit_kernel<<<dim3(7, 8, 8), 256, 0, stream>>>(mem[0], mem0s, 256, 196, 256 * 196, 196 * 512);
  tsplit_kernel<<<dim3(25, 8, 8), 256, 0, stream>>>(mem[1], mem1s, 256, 784, 256 * 784, 784 * 512);
  tsplit_kernel<<<dim3(98, 8, 8), 256, 0, stream>>>(mem[2], mem2s, 256, 3136, 256 * 3136, 3136 * 512);

  initq_kernel<<<800, 256, 0, stream>>>(qf, qe, q);

  const int Ps[3] = {196, 784, 3136};
  const int ohs[3] = {14, 28, 56};
  const int Ss[3] = {1, 2, 5};
  for (int i = 0; i < L_; ++i) {
    const int mi = i % 3, P = Ps[mi], oh = ohs[mi];
    const int Pw = (P + 31) >> 5;
    const int S = Ss[mi];
    const int ntiles = (P + KT_ - 1) / KT_;
    const int tps = (ntiles + S - 1) / S;
    if (i > 0) maskbias_kernel<<<800, 256, 0, stream>>>(out_mask, biasbits, oh);
    // ---- cross-attention ----
    mg(stream, 0, 0, false, 0, q, W2ca + (size_t)(i * 3) * 131072, ca_bqkv + i * 768, qh,
       800, 256, 256, 1, 0, 0, 0, 256);
    mg(stream, 1, 0, false, 1, memsp[mi], W2ca + (size_t)(i * 3 + 1) * 131072,
       ca_bqkv + i * 768 + 256, kvb,
       P, 512, 256, B_, (long long)P * 512, 0, (long long)P * 512, 512);
    {
      dim3 ag(64, 4, S);
      if (S > 1) {
        if (i > 0)
          fattn_kernel<true, true, true><<<ag, 256, 0, stream>>>(
              qh, 256, kvb, 512, kvb + 256, 512, biasbits, part, P, Pw, tps, S);
        else
          fattn_kernel<false, true, true><<<ag, 256, 0, stream>>>(
              qh, 256, kvb, 512, kvb + 256, 512, nullptr, part, P, Pw, tps, S);
        attncomb_kernel<<<800, 256, 0, stream>>>(part, attn_o, S, 4);
      } else {
        if (i > 0)
          fattn_kernel<true, true, false><<<ag, 256, 0, stream>>>(
              qh, 256, kvb, 512, kvb + 256, 512, biasbits, attn_o, P, Pw, tps, S);
        else
          fattn_kernel<false, true, false><<<ag, 256, 0, stream>>>(
              qh, 256, kvb, 512, kvb + 256, 512, nullptr, attn_o, P, Pw, tps, S);
      }
    }
    mg(stream, 0, 0, false, 0, attn_o, W2cao + (size_t)i * 131072, ca_bo + i * 256, tmp,
       800, 256, 256, 1, 0, 0, 0, 256);
    ln_kernel<true><<<800, 256, 0, stream>>>(q, tmp, ca_ln_s + i * 256, ca_ln_b + i * 256, q);
    // ---- self-attention ----
    mg(stream, 0, 0, false, 0, q, W2sa + (size_t)(i * 3) * 131072, sa_bqkv + i * 768, qkvbuf,
       800, 768, 256, 1, 0, 0, 0, 768);
    fattn_kernel<false, false, false><<<dim3(64, 4, 1), 256, 0, stream>>>(
        qkvbuf, 768, qkvbuf + 256, 768, qkvbuf + 512, 768, nullptr, attn_o, 100, 4, 1, 1);
    mg(stream, 0, 0, false, 0, attn_o, W2sao + (size_t)i * 131072, sa_bo + i * 256, tmp,
       800, 256, 256, 1, 0, 0, 0, 256);
    ln_kernel<true><<<800, 256, 0, stream>>>(q, tmp, sa_ln_s + i * 256, sa_ln_b + i * 256, q);
    // ---- FFN ----
    mg(stream, 0, 0, true, 0, q, W2f1 + (size_t)i * 1048576, ffn_b1 + i * 2048, ffnh,
       800, 2048, 256, 1, 0, 0, 0, 2048);
    mg(stream, 0, 0, false, 0, ffnh, W2f2 + (size_t)i * 1048576, ffn_b2 + i * 256, tmp,
       800, 256, 2048, 1, 0, 0, 0, 256);
    ln_kernel<true><<<800, 256, 0, stream>>>(q, tmp, ffn_ln_s + i * 256, ffn_ln_b + i * 256, q);
    // ---- mask head ----
    ln_kernel<false><<<800, 256, 0, stream>>>(q, nullptr, dec_ln_s, dec_ln_b, nq);
    mg(stream, 0, 0, true, 0, nq, W2me, me_b1, me1, 800, 256, 256, 1, 0, 0, 0, 256);
    mg(stream, 0, 0, true, 0, me1, W2me + 131072, me_b2, me2, 800, 256, 256, 1, 0, 0, 0, 256);
    mg(stream, 0, 0, false, 0, me2, W2me + 262144, me_b3, me3, 800, 256, 256, 1, 0, 0, 0, 256);
    mg(stream, 0, 1, false, 0, me3, mask_features, nullptr, out_mask,
       100, 12544, 256, B_, (long long)100 * 256, (long long)256 * 12544,
       (long long)100 * 12544, 12544);
  }
  gemm32_kernel<<<dim3(3, 13, 1), 256, 0, stream>>>(nq, cls_w, cls_b, out_logits, 800, C_, 256);
}

// Round 6
// 3682.132 us; speedup vs baseline: 1.1427x; 1.0960x over previous
//
#include <hip/hip_runtime.h>
#include <cmath>

#define B_ 8
#define Q_ 100
#define D_ 256
#define H_ 8
#define HD_ 32
#define L_ 9
#define F_ 2048
#define C_ 151
#define HM_ 112
#define PMAX_ 3136
#define QT_ 32
#define KT_ 128
#define RECSZ 1088   // 32 m + 32 l + 32*32 O

typedef __attribute__((ext_vector_type(4))) short s4v;
typedef __attribute__((ext_vector_type(8))) short s8v;
typedef __attribute__((ext_vector_type(4))) float f4v;

__device__ __forceinline__ unsigned short f2bf(float x) {
  unsigned int u = __float_as_uint(x);
  return (unsigned short)((u + 0x7fffu + ((u >> 16) & 1u)) >> 16);
}
__device__ __forceinline__ float bf2f(unsigned short h) {
  return __uint_as_float(((unsigned int)h) << 16);
}
__device__ __forceinline__ void split2(float x, short& h, short& l) {
  unsigned short hb = f2bf(x);
  float r = x - bf2f(hb);
  h = (short)hb;
  l = (short)f2bf(r);
}

__device__ __forceinline__ float block_sum(float v, float* red) {
  int t = threadIdx.x;
  red[t] = v; __syncthreads();
  for (int s = 128; s > 0; s >>= 1) {
    if (t < s) red[t] += red[t + s];
    __syncthreads();
  }
  float r = red[0]; __syncthreads();
  return r;
}

// ---------------- init q ----------------
__global__ __launch_bounds__(256) void initq_kernel(const float* __restrict__ qf,
                                                    const float* __restrict__ qe,
                                                    float* __restrict__ q) {
  int idx = blockIdx.x * 256 + threadIdx.x;
  int qd = idx % (Q_ * D_);
  q[idx] = qf[qd] + qe[qd];
}

// ---------------- transpose-split: fp32 [K][N] -> bf16 [N][2K] ----------------
__global__ __launch_bounds__(256) void tsplit_kernel(
    const float* __restrict__ in, short* __restrict__ out,
    int K, int N, long long ibs, long long obs) {
  __shared__ float tile[32][33];
  const int z = blockIdx.z;
  const int nb = blockIdx.x * 32, kb = blockIdx.y * 32;
  const float* I = in + (size_t)z * ibs;
  short* O = out + (size_t)z * obs;
  const int t = threadIdx.x;
  {
    const int r = t >> 3, c = (t & 7) * 4;
    const int gk = kb + r;
#pragma unroll
    for (int j = 0; j < 4; ++j) {
      int gn = nb + c + j;
      tile[r][c + j] = (gk < K && gn < N) ? I[(size_t)gk * N + gn] : 0.f;
    }
  }
  __syncthreads();
  {
    const int nr = t >> 3, kc = (t & 7) * 4;
    const int gn = nb + nr;
    if (gn < N) {
#pragma unroll
      for (int j = 0; j < 4; ++j) {
        int gk = kb + kc + j;
        if (gk < K) {
          short h, l; split2(tile[kc + j][nr], h, l);
          O[(size_t)gn * 2 * K + gk] = h;
          O[(size_t)gn * 2 * K + K + gk] = l;
        }
      }
    }
  }
}

// ---------------- MFMA bf16x3 GEMM ----------------
__device__ __forceinline__ s8v ldfrag(const short* p) {
  s4v lo = *(const s4v*)p;
  s4v hi = *(const s4v*)(p + 16);
  return __builtin_shufflevector(lo, hi, 0, 1, 2, 3, 4, 5, 6, 7);
}

// BM in {32,64}. AMODE: 0 fp32 A, 1 pre-split bf16 A. WMODE: 0 pre-split W, 1 fp32 W.
// OUT: 0 fp32 store, 1 bf16 store.
template <int BM, int AMODE, int WMODE, bool RELU, int OUT>
__global__ __launch_bounds__(256) void mgemm_kernel(
    const void* __restrict__ Ap, const void* __restrict__ Wp,
    const float* __restrict__ bias, void* __restrict__ Cv,
    int M, int N, int K,
    long long Abs, long long Wbs, long long Cbs, int ldc) {
  constexpr int MI = BM / 32;
  __shared__ short Ah[BM * 36], Al[BM * 36], Wh[128 * 36], Wl[128 * 36];
  const int z = blockIdx.z;
  const int n0 = blockIdx.x * 128, m0 = blockIdx.y * BM;
  const int t = threadIdx.x;
  const int lane = t & 63;
  const int wave = t >> 6;
  const int wm = wave >> 1, wn = wave & 1;
  const int lr = lane & 15, lg = lane >> 4;
  f4v acc[MI][4];
#pragma unroll
  for (int i = 0; i < MI; ++i)
#pragma unroll
    for (int j = 0; j < 4; ++j) acc[i][j] = (f4v){0.f, 0.f, 0.f, 0.f};

  for (int k0 = 0; k0 < K; k0 += 32) {
    // ---- stage A ----
    if (AMODE == 0) {
      const float* A = (const float*)Ap + (size_t)z * Abs;
      if (BM == 64) {
        const int arow = t >> 2;
        const int kc = (t & 3) * 8;
        float x[8];
        if (m0 + arow < M) {
          const float* ap = A + (size_t)(m0 + arow) * K + k0 + kc;
          *(f4v*)&x[0] = *(const f4v*)ap;
          *(f4v*)&x[4] = *(const f4v*)(ap + 4);
        } else {
#pragma unroll
          for (int e = 0; e < 8; ++e) x[e] = 0.f;
        }
        s4v h0, h1, l0, l1;
#pragma unroll
        for (int e = 0; e < 4; ++e) { short hh, ll; split2(x[e], hh, ll); h0[e] = hh; l0[e] = ll; }
#pragma unroll
        for (int e = 0; e < 4; ++e) { short hh, ll; split2(x[4 + e], hh, ll); h1[e] = hh; l1[e] = ll; }
        *(s4v*)&Ah[arow * 36 + kc] = h0; *(s4v*)&Ah[arow * 36 + kc + 4] = h1;
        *(s4v*)&Al[arow * 36 + kc] = l0; *(s4v*)&Al[arow * 36 + kc + 4] = l1;
      } else {
        const int arow = t >> 3;
        const int kc = (t & 7) * 4;
        float x[4];
        if (m0 + arow < M) {
          *(f4v*)&x[0] = *(const f4v*)(A + (size_t)(m0 + arow) * K + k0 + kc);
        } else {
#pragma unroll
          for (int e = 0; e < 4; ++e) x[e] = 0.f;
        }
        s4v h0, l0;
#pragma unroll
        for (int e = 0; e < 4; ++e) { short hh, ll; split2(x[e], hh, ll); h0[e] = hh; l0[e] = ll; }
        *(s4v*)&Ah[arow * 36 + kc] = h0;
        *(s4v*)&Al[arow * 36 + kc] = l0;
      }
    } else {
      const short* A2 = (const short*)Ap + (size_t)z * Abs;
      const int arow = t >> 2;
      const int c = t & 3, sel = c >> 1, ko = (c & 1) * 16;
      s8v v0 = {0, 0, 0, 0, 0, 0, 0, 0}, v1 = {0, 0, 0, 0, 0, 0, 0, 0};
      if (m0 + arow < M) {
        const short* ap = A2 + (size_t)(m0 + arow) * (2 * K) + sel * K + k0 + ko;
        v0 = *(const s8v*)ap;
        v1 = *(const s8v*)(ap + 8);
      }
      short* dst = sel ? Al : Ah;
      *(s4v*)&dst[arow * 36 + ko] = __builtin_shufflevector(v0, v0, 0, 1, 2, 3);
      *(s4v*)&dst[arow * 36 + ko + 4] = __builtin_shufflevector(v0, v0, 4, 5, 6, 7);
      *(s4v*)&dst[arow * 36 + ko + 8] = __builtin_shufflevector(v1, v1, 0, 1, 2, 3);
      *(s4v*)&dst[arow * 36 + ko + 12] = __builtin_shufflevector(v1, v1, 4, 5, 6, 7);
    }
    // ---- stage W ----
    if (WMODE == 0) {
      const short* W2 = (const short*)Wp + (size_t)z * Wbs;
      const int n = t >> 1, sel = t & 1;
      const short* wp = W2 + (size_t)(n0 + n) * (2 * K) + sel * K + k0;
      short* dst = sel ? Wl : Wh;
#pragma unroll
      for (int j = 0; j < 4; ++j) {
        s8v v = *(const s8v*)(wp + j * 8);
        *(s4v*)&dst[n * 36 + j * 8] = __builtin_shufflevector(v, v, 0, 1, 2, 3);
        *(s4v*)&dst[n * 36 + j * 8 + 4] = __builtin_shufflevector(v, v, 4, 5, 6, 7);
      }
    } else {
      const float* W = (const float*)Wp + (size_t)z * Wbs;
      const int kr = t >> 3, c0 = (t & 7) * 16;
      const float* wp = W + (size_t)(k0 + kr) * N + n0 + c0;
      float x[16];
#pragma unroll
      for (int j = 0; j < 4; ++j) *(f4v*)&x[j * 4] = *(const f4v*)(wp + j * 4);
#pragma unroll
      for (int j = 0; j < 16; ++j) {
        short hh, ll; split2(x[j], hh, ll);
        Wh[(c0 + j) * 36 + kr] = hh;
        Wl[(c0 + j) * 36 + kr] = ll;
      }
    }
    __syncthreads();
    s8v whf[4], wlf[4];
#pragma unroll
    for (int ni = 0; ni < 4; ++ni) {
      whf[ni] = ldfrag(&Wh[(wn * 64 + ni * 16 + lr) * 36 + 4 * lg]);
      wlf[ni] = ldfrag(&Wl[(wn * 64 + ni * 16 + lr) * 36 + 4 * lg]);
    }
#pragma unroll
    for (int mi = 0; mi < MI; ++mi) {
      s8v ah = ldfrag(&Ah[(wm * (BM / 2) + mi * 16 + lr) * 36 + 4 * lg]);
      s8v al = ldfrag(&Al[(wm * (BM / 2) + mi * 16 + lr) * 36 + 4 * lg]);
#pragma unroll
      for (int ni = 0; ni < 4; ++ni) {
        acc[mi][ni] = __builtin_amdgcn_mfma_f32_16x16x32_bf16(ah, whf[ni], acc[mi][ni], 0, 0, 0);
        acc[mi][ni] = __builtin_amdgcn_mfma_f32_16x16x32_bf16(al, whf[ni], acc[mi][ni], 0, 0, 0);
        acc[mi][ni] = __builtin_amdgcn_mfma_f32_16x16x32_bf16(ah, wlf[ni], acc[mi][ni], 0, 0, 0);
      }
    }
    __syncthreads();
  }
  float* Cf = (float*)Cv + (size_t)z * Cbs;
  unsigned short* Ch = (unsigned short*)Cv + (size_t)z * Cbs;
#pragma unroll
  for (int mi = 0; mi < MI; ++mi) {
#pragma unroll
    for (int i = 0; i < 4; ++i) {
      int row = m0 + wm * (BM / 2) + mi * 16 + 4 * lg + i;
      if (row >= M) continue;
#pragma unroll
      for (int ni = 0; ni < 4; ++ni) {
        int col = n0 + wn * 64 + ni * 16 + lr;
        float v = acc[mi][ni][i] + (bias ? bias[col] : 0.f);
        if (RELU) v = fmaxf(v, 0.f);
        if (OUT == 0) Cf[(size_t)row * ldc + col] = v;
        else Ch[(size_t)row * ldc + col] = f2bf(v);
      }
    }
  }
}

// ---------------- fp32 GEMM (cls head only) ----------------
__global__ __launch_bounds__(256) void gemm32_kernel(
    const float* __restrict__ A, const float* __restrict__ W,
    const float* __restrict__ bias, float* __restrict__ C,
    int M, int N, int K) {
  __shared__ float As[16][65];
  __shared__ float Ws[16][65];
  const int n0 = blockIdx.x * 64, m0 = blockIdx.y * 64;
  const int t = threadIdx.x;
  const int tm = t >> 4, tn = t & 15;
  float acc[4][4] = {};
  for (int k0 = 0; k0 < K; k0 += 16) {
#pragma unroll
    for (int l = 0; l < 4; ++l) {
      int idx = t + l * 256;
      int am = idx >> 4, ak = idx & 15;
      int gm = m0 + am, gk = k0 + ak;
      As[ak][am] = (gm < M) ? A[(size_t)gm * K + gk] : 0.f;
      int wk = idx >> 6, wn = idx & 63;
      int gn = n0 + wn, gk2 = k0 + wk;
      Ws[wk][wn] = (gn < N) ? W[(size_t)gk2 * N + gn] : 0.f;
    }
    __syncthreads();
#pragma unroll
    for (int kk = 0; kk < 16; ++kk) {
      float a[4], b[4];
#pragma unroll
      for (int i = 0; i < 4; ++i) a[i] = As[kk][tm * 4 + i];
#pragma unroll
      for (int j = 0; j < 4; ++j) b[j] = Ws[kk][tn * 4 + j];
#pragma unroll
      for (int i = 0; i < 4; ++i)
#pragma unroll
        for (int j = 0; j < 4; ++j) acc[i][j] += a[i] * b[j];
    }
    __syncthreads();
  }
#pragma unroll
  for (int i = 0; i < 4; ++i) {
    int gm = m0 + tm * 4 + i;
    if (gm >= M) continue;
#pragma unroll
    for (int j = 0; j < 4; ++j) {
      int gn = n0 + tn * 4 + j;
      if (gn >= N) continue;
      C[(size_t)gm * N + gn] = acc[i][j] + bias[gn];
    }
  }
}

// ---------------- residual + LN: one wave per row, no barriers ----------------
template <bool RES>
__global__ __launch_bounds__(256) void ln_kernel(const float* __restrict__ x,
                                                 const float* __restrict__ r,
                                                 const float* __restrict__ s,
                                                 const float* __restrict__ b,
                                                 float* __restrict__ out, int nrows) {
  const int wave = threadIdx.x >> 6, lane = threadIdx.x & 63;
  const int row = blockIdx.x * 4 + wave;
  if (row >= nrows) return;
  f4v v = *((const f4v*)(x + (size_t)row * D_) + lane);
  if (RES) {
    f4v rv = *((const f4v*)(r + (size_t)row * D_) + lane);
    v[0] += rv[0]; v[1] += rv[1]; v[2] += rv[2]; v[3] += rv[3];
  }
  float sum = v[0] + v[1] + v[2] + v[3];
#pragma unroll
  for (int off = 32; off > 0; off >>= 1) sum += __shfl_xor(sum, off, 64);
  float mean = sum * (1.f / D_);
  float c0 = v[0] - mean, c1 = v[1] - mean, c2 = v[2] - mean, c3 = v[3] - mean;
  float vs = c0 * c0 + c1 * c1 + c2 * c2 + c3 * c3;
#pragma unroll
  for (int off = 32; off > 0; off >>= 1) vs += __shfl_xor(vs, off, 64);
  float inv = rsqrtf(vs * (1.f / D_) + 1e-5f);
  f4v sv = *((const f4v*)s + lane);
  f4v bv = *((const f4v*)b + lane);
  f4v o;
  o[0] = c0 * inv * sv[0] + bv[0];
  o[1] = c1 * inv * sv[1] + bv[1];
  o[2] = c2 * inv * sv[2] + bv[2];
  o[3] = c3 * inv * sv[3] + bv[3];
  *((f4v*)(out + (size_t)row * D_) + lane) = o;
}

// ---------------- flash attention v4: per-thread online softmax ----------------
// grid (64 = b*8+h, q-tiles, S). 256 thr: r = t&31 (q-row), c8 = t>>5 (k-slice).
// Each thread keeps its own (m,l,O) over its 16-key slices; merge once at end.
template <bool BIAS, bool KVBF16, bool SPLIT>
__global__ __launch_bounds__(256) void fattn_kernel(
    const float* __restrict__ qb, int ldq,
    const void* __restrict__ kbv, int ldk,
    const void* __restrict__ vbv, int ldv,
    const unsigned int* __restrict__ bits,
    float* __restrict__ outp, int P, int Pw, int tps, int S) {
  __shared__ float smem[2 * KT_ * 36];
  __shared__ float red[256];
  __shared__ float lsave[QT_];
  __shared__ unsigned int bb[QT_ * 4];
  float* Kt = smem;
  float* Vt = smem + KT_ * 36;
  const int b = blockIdx.x >> 3, h = blockIdx.x & 7;
  const int q0 = blockIdx.y * QT_;
  const int seg = blockIdx.z;
  const int kbeg = seg * tps * KT_;
  const int kend = min(P, kbeg + tps * KT_);
  const int t = threadIdx.x;
  const int r = t & 31, c8 = t >> 5;
  const int qrow = q0 + r;
  const int qcl = (qrow < Q_) ? qrow : 0;
  float4 qreg[8];
  {
    const float4* qp = reinterpret_cast<const float4*>(qb + (size_t)(b * Q_ + qcl) * ldq + h * HD_);
#pragma unroll
    for (int e = 0; e < 8; ++e) qreg[e] = qp[e];
  }
  float m = -3.0e38f, l = 0.f;
  float O[32];
#pragma unroll
  for (int e = 0; e < 32; ++e) O[e] = 0.f;
  const float scale = 0.17677669529663687f;

  for (int k0 = kbeg; k0 < kend; k0 += KT_) {
    if (KVBF16) {
      const unsigned short* kb = (const unsigned short*)kbv;
      const unsigned short* vb = (const unsigned short*)vbv;
#pragma unroll
      for (int i = 0; i < 2; ++i) {
        int cid = t + i * 256;
        int row = cid >> 2, c = (cid & 3) * 8;
        int gk = k0 + row;
        float kx[8], vx[8];
        if (gk < kend) {
          s8v kv8 = *(const s8v*)(kb + (size_t)(b * P + gk) * ldk + h * HD_ + c);
          s8v vv8 = *(const s8v*)(vb + (size_t)(b * P + gk) * ldv + h * HD_ + c);
#pragma unroll
          for (int e = 0; e < 8; ++e) { kx[e] = bf2f((unsigned short)kv8[e]); vx[e] = bf2f((unsigned short)vv8[e]); }
        } else {
#pragma unroll
          for (int e = 0; e < 8; ++e) { kx[e] = 0.f; vx[e] = 0.f; }
        }
        *(f4v*)&Kt[row * 36 + c] = *(f4v*)&kx[0];
        *(f4v*)&Kt[row * 36 + c + 4] = *(f4v*)&kx[4];
        *(f4v*)&Vt[row * 36 + c] = *(f4v*)&vx[0];
        *(f4v*)&Vt[row * 36 + c + 4] = *(f4v*)&vx[4];
      }
    } else {
      const float* kb = (const float*)kbv;
      const float* vb = (const float*)vbv;
#pragma unroll
      for (int i = 0; i < 4; ++i) {
        int f = t + i * 256;
        int row = f >> 3, c4 = (f & 7) * 4;
        int gk = k0 + row;
        float4 kvv = make_float4(0.f, 0.f, 0.f, 0.f);
        float4 vvv = kvv;
        if (gk < kend) {
          kvv = *reinterpret_cast<const float4*>(kb + (size_t)(b * P + gk) * ldk + h * HD_ + c4);
          vvv = *reinterpret_cast<const float4*>(vb + (size_t)(b * P + gk) * ldv + h * HD_ + c4);
        }
        *reinterpret_cast<float4*>(&Kt[row * 36 + c4]) = kvv;
        *reinterpret_cast<float4*>(&Vt[row * 36 + c4]) = vvv;
      }
    }
    if (BIAS && t < QT_ * 4) {
      int r2 = t >> 2, w = t & 3;
      int gr = q0 + r2, wi = (k0 >> 5) + w;
      bb[t] = (gr < Q_ && wi < Pw) ? bits[(size_t)(b * Q_ + gr) * Pw + wi] : 0u;
    }
    __syncthreads();
    float p[16];
    float pmax = -3.0e38f;
#pragma unroll
    for (int j = 0; j < 16; ++j) {
      int kk = c8 * 16 + j;
      int gkk = k0 + kk;
      const float4* kp = reinterpret_cast<const float4*>(&Kt[kk * 36]);
      float s = 0.f;
#pragma unroll
      for (int e = 0; e < 8; ++e) {
        float4 kv4 = kp[e];
        s += qreg[e].x * kv4.x + qreg[e].y * kv4.y + qreg[e].z * kv4.z + qreg[e].w * kv4.w;
      }
      s *= scale;
      if (BIAS) {
        unsigned int word = bb[r * 4 + (kk >> 5)];
        if ((word >> (kk & 31)) & 1u) s += -1e9f;
      }
      if (gkk >= kend) s = -3.0e38f;
      p[j] = s;
      pmax = fmaxf(pmax, s);
    }
    float mnew = fmaxf(m, pmax);
    float corr = __expf(m - mnew);
    m = mnew;
    float lsum = 0.f;
#pragma unroll
    for (int j = 0; j < 16; ++j) {
      p[j] = __expf(p[j] - mnew);
      lsum += p[j];
    }
    l = l * corr + lsum;
#pragma unroll
    for (int e = 0; e < 32; ++e) O[e] *= corr;
#pragma unroll
    for (int j = 0; j < 16; ++j) {
      int kk = c8 * 16 + j;
      const float4* vp = reinterpret_cast<const float4*>(&Vt[kk * 36]);
      float pj = p[j];
#pragma unroll
      for (int e = 0; e < 8; ++e) {
        float4 vv = vp[e];
        O[e * 4 + 0] += pj * vv.x;
        O[e * 4 + 1] += pj * vv.y;
        O[e * 4 + 2] += pj * vv.z;
        O[e * 4 + 3] += pj * vv.w;
      }
    }
    __syncthreads();
  }
  // ---- merge the 8 per-thread slices of each row (once per kernel) ----
  red[t] = m;
  __syncthreads();
#pragma unroll
  for (int s = 4; s > 0; s >>= 1) {
    if (c8 < s) red[t] = fmaxf(red[t], red[t + (s << 5)]);
    __syncthreads();
  }
  float M = red[r];
  __syncthreads();
  float w = __expf(m - M);
  red[t] = w * l;
  __syncthreads();
#pragma unroll
  for (int s = 4; s > 0; s >>= 1) {
    if (c8 < s) red[t] += red[t + (s << 5)];
    __syncthreads();
  }
  if (t < QT_) lsave[t] = red[t];
  float* part = SPLIT
      ? outp + ((size_t)((blockIdx.x * gridDim.y + blockIdx.y) * S + seg)) * RECSZ
      : nullptr;
  if (SPLIT && t < QT_) {
    part[t] = M;            // row t's max (thread t has r==t)
    part[32 + t] = red[t];  // l_tot relative to M
  }
  float* sc = smem;
#pragma unroll
  for (int e = 0; e < 32; ++e) sc[t * 33 + e] = w * O[e];
  __syncthreads();
  for (int o = t; o < QT_ * 32; o += 256) {
    int ro = o >> 5, eo = o & 31;
    float sacc = 0.f;
#pragma unroll
    for (int c = 0; c < 8; ++c) sacc += sc[(c * 32 + ro) * 33 + eo];
    if (SPLIT) {
      part[64 + o] = sacc;
    } else if (q0 + ro < Q_) {
      outp[(size_t)(b * Q_ + q0 + ro) * D_ + h * HD_ + eo] = sacc / lsave[ro];
    }
  }
}

// ---------------- split-K combine ----------------
__global__ __launch_bounds__(256) void attncomb_kernel(
    const float* __restrict__ part, float* __restrict__ out, int S, int nqt) {
  const int row = blockIdx.x;               // b*Q + q
  const int b = row / Q_, qq = row % Q_;
  const int t = threadIdx.x;
  const int h = t >> 5, d = t & 31;
  const int qt = qq >> 5, r = qq & 31;
  const float* base = part + ((size_t)((b * 8 + h) * nqt + qt) * S) * RECSZ;
  float M = -3.0e38f;
  for (int s = 0; s < S; ++s) M = fmaxf(M, base[(size_t)s * RECSZ + r]);
  float lt = 0.f, Ov = 0.f;
  for (int s = 0; s < S; ++s) {
    const float* rec = base + (size_t)s * RECSZ;
    float w = __expf(rec[r] - M);
    lt += w * rec[32 + r];
    Ov += w * rec[64 + r * 32 + d];
  }
  out[(size_t)row * D_ + h * HD_ + d] = Ov / lt;
}

// ---------------- attention-bias from prev mask (packed bits) ----------------
__global__ __launch_bounds__(256) void maskbias_kernel(
    const float* __restrict__ prev,
    unsigned int* __restrict__ bias,
    int oh) {
  __shared__ float pm[HM_ * HM_];
  __shared__ float rbuf[PMAX_];
  __shared__ float red[256];
  __shared__ unsigned int bw[128];
  const int row = blockIdx.x;
  const int t = threadIdx.x;
  const float* src = prev + (size_t)row * (HM_ * HM_);
  for (int i = t; i < HM_ * HM_; i += 256) pm[i] = src[i];
  __syncthreads();
  const int ratio = HM_ / oh;
  const int taps = 2 * ratio;
  const float invr = 1.f / (float)ratio;
  const int P = oh * oh;
  const int Pw = (P + 31) >> 5;
  float nign = 0.f;
  for (int p = t; p < P; p += 256) {
    int oy = p / oh, ox = p - oy * oh;
    float sy = (oy + 0.5f) * ratio - 0.5f;
    float sx = (ox + 0.5f) * ratio - 0.5f;
    int y0 = (int)floorf(sy - ratio) + 1;
    int x0 = (int)floorf(sx - ratio) + 1;
    float wxs = 0.f;
    for (int si = 0; si < taps; ++si) {
      int x = x0 + si;
      if (x < 0 || x >= HM_) continue;
      wxs += 1.f - fabsf(sx - x) * invr;
    }
    float acc = 0.f, wys = 0.f;
    for (int ti = 0; ti < taps; ++ti) {
      int y = y0 + ti;
      if (y < 0 || y >= HM_) continue;
      float wy = 1.f - fabsf(sy - y) * invr;
      wys += wy;
      float ra = 0.f;
      const float* pr = pm + y * HM_;
      for (int si = 0; si < taps; ++si) {
        int x = x0 + si;
        if (x < 0 || x >= HM_) continue;
        float wx = 1.f - fabsf(sx - x) * invr;
        ra += wx * pr[x];
      }
      acc += wy * ra;
    }
    float rv = acc / (wys * wxs);
    rbuf[p] = rv;
    if (!(rv < 0.f)) nign += 1.f;
  }
  float tot = block_sum(nign, red);
  bool fully = (tot == 0.f);
  for (int w = t; w < Pw; w += 256) bw[w] = 0u;
  __syncthreads();
  if (!fully) {
    for (int p = t; p < P; p += 256) {
      if (rbuf[p] < 0.f) atomicOr(&bw[p >> 5], 1u << (p & 31));
    }
  }
  __syncthreads();
  unsigned int* dst = bias + (size_t)row * Pw;
  for (int w = t; w < Pw; w += 256) dst[w] = bw[w];
}

// ---------------- host dispatch ----------------
static inline void mg(hipStream_t st, int bm, int amode, int wmode, bool relu,
                      const void* A, const void* W, const float* bias, void* C,
                      int M, int N, int K, int Z,
                      long long Abs, long long Wbs, long long Cbs, int ldc) {
  dim3 g(N / 128, (M + bm - 1) / bm, Z);
  if (bm == 32) {
    if (relu)
      mgemm_kernel<32, 0, 0, true, 0><<<g, 256, 0, st>>>(A, W, bias, C, M, N, K, Abs, Wbs, Cbs, ldc);
    else
      mgemm_kernel<32, 0, 0, false, 0><<<g, 256, 0, st>>>(A, W, bias, C, M, N, K, Abs, Wbs, Cbs, ldc);
  } else {
    if (amode == 1)
      mgemm_kernel<64, 1, 0, false, 1><<<g, 256, 0, st>>>(A, W, bias, C, M, N, K, Abs, Wbs, Cbs, ldc);
    else if (wmode == 1)
      mgemm_kernel<64, 0, 1, false, 0><<<g, 256, 0, st>>>(A, W, bias, C, M, N, K, Abs, Wbs, Cbs, ldc);
    else
      mgemm_kernel<64, 0, 0, false, 0><<<g, 256, 0, st>>>(A, W, bias, C, M, N, K, Abs, Wbs, Cbs, ldc);
  }
}

extern "C" void kernel_launch(void* const* d_in, const int* in_sizes, int n_in,
                              void* d_out, int out_size, void* d_ws, size_t ws_size,
                              hipStream_t stream) {
  const float* mask_features = (const float*)d_in[0];
  const float* mem[3] = {(const float*)d_in[1], (const float*)d_in[2], (const float*)d_in[3]};
  const float* qf = (const float*)d_in[4];
  const float* qe = (const float*)d_in[5];
  const float* ca_wqkv = (const float*)d_in[6];
  const float* ca_bqkv = (const float*)d_in[7];
  const float* ca_wo = (const float*)d_in[8];
  const float* ca_bo = (const float*)d_in[9];
  const float* ca_ln_s = (const float*)d_in[10];
  const float* ca_ln_b = (const float*)d_in[11];
  const float* sa_wqkv = (const float*)d_in[12];
  const float* sa_bqkv = (const float*)d_in[13];
  const float* sa_wo = (const float*)d_in[14];
  const float* sa_bo = (const float*)d_in[15];
  const float* sa_ln_s = (const float*)d_in[16];
  const float* sa_ln_b = (const float*)d_in[17];
  const float* ffn_w1 = (const float*)d_in[18];
  const float* ffn_b1 = (const float*)d_in[19];
  const float* ffn_w2 = (const float*)d_in[20];
  const float* ffn_b2 = (const float*)d_in[21];
  const float* ffn_ln_s = (const float*)d_in[22];
  const float* ffn_ln_b = (const float*)d_in[23];
  const float* dec_ln_s = (const float*)d_in[24];
  const float* dec_ln_b = (const float*)d_in[25];
  const float* me_w1 = (const float*)d_in[26];
  const float* me_b1 = (const float*)d_in[27];
  const float* me_w2 = (const float*)d_in[28];
  const float* me_b2 = (const float*)d_in[29];
  const float* me_w3 = (const float*)d_in[30];
  const float* me_b3 = (const float*)d_in[31];
  const float* cls_w = (const float*)d_in[32];
  const float* cls_b = (const float*)d_in[33];

  float* out_logits = (float*)d_out;
  float* out_mask = (float*)d_out + (size_t)800 * C_;

  float* fws = (float*)d_ws;
  float* q      = fws; fws += (size_t)800 * D_;
  float* qh     = fws; fws += (size_t)800 * D_;
  float* attn_o = fws; fws += (size_t)800 * D_;
  float* tmp    = fws; fws += (size_t)800 * D_;
  float* nq     = fws; fws += (size_t)800 * D_;
  float* me1    = fws; fws += (size_t)800 * D_;
  float* me2    = fws; fws += (size_t)800 * D_;
  float* me3    = fws; fws += (size_t)800 * D_;
  float* kvbuf  = fws; fws += (size_t)B_ * PMAX_ * 256;    // bf16 [B][P][512]
  float* qkvbuf = fws; fws += (size_t)800 * 768;
  float* biasb  = fws; fws += (size_t)800 * 128;
  float* ffnh   = fws; fws += (size_t)B_ * Q_ * F_;
  float* part   = fws; fws += (size_t)64 * 4 * 5 * RECSZ;

  unsigned short* kvb = (unsigned short*)kvbuf;
  unsigned int* biasbits = (unsigned int*)biasb;

  short* sws = (short*)fws;
  short* W2ca  = sws; sws += (size_t)27 * 256 * 512;
  short* W2sa  = sws; sws += (size_t)27 * 256 * 512;
  short* W2cao = sws; sws += (size_t)9 * 256 * 512;
  short* W2sao = sws; sws += (size_t)9 * 256 * 512;
  short* W2f1  = sws; sws += (size_t)9 * 2048 * 512;
  short* W2f2  = sws; sws += (size_t)9 * 256 * 4096;
  short* W2me  = sws; sws += (size_t)3 * 256 * 512;
  short* mem2s = sws; sws += (size_t)B_ * 3136 * 512;
  short* mem1s = sws; sws += (size_t)B_ * 784 * 512;
  short* mem0s = sws; sws += (size_t)B_ * 196 * 512;
  short* memsp[3] = {mem0s, mem1s, mem2s};
  // optional: pre-split mask_features (bf16 [B][12544][512]) if workspace allows
  short* maskfs = sws; sws += (size_t)B_ * 12544 * 512;
  const bool presplit = ((size_t)((char*)sws - (char*)d_ws) <= ws_size);

  tsplit_kernel<<<dim3(8, 8, 27), 256, 0, stream>>>(ca_wqkv, W2ca, 256, 256, 65536, 131072);
  tsplit_kernel<<<dim3(8, 8, 27), 256, 0, stream>>>(sa_wqkv, W2sa, 256, 256, 65536, 131072);
  tsplit_kernel<<<dim3(8, 8, 9), 256, 0, stream>>>(ca_wo, W2cao, 256, 256, 65536, 131072);
  tsplit_kernel<<<dim3(8, 8, 9), 256, 0, stream>>>(sa_wo, W2sao, 256, 256, 65536, 131072);
  tsplit_kernel<<<dim3(64, 8, 9), 256, 0, stream>>>(ffn_w1, W2f1, 256, 2048, 524288, 1048576);
  tsplit_kernel<<<dim3(8, 64, 9), 256, 0, stream>>>(ffn_w2, W2f2, 2048, 256, 524288, 1048576);
  tsplit_kernel<<<dim3(8, 8, 1), 256, 0, stream>>>(me_w1, W2me, 256, 256, 0, 0);
  tsplit_kernel<<<dim3(8, 8, 1), 256, 0, stream>>>(me_w2, W2me + 131072, 256, 256, 0, 0);
  tsplit_kernel<<<dim3(8, 8, 1), 256, 0, stream>>>(me_w3, W2me + 262144, 256, 256, 0, 0);
  tsplit_kernel<<<dim3(7, 8, 8), 256, 0, stream>>>(mem[0], mem0s, 256, 196, 256 * 196, 196 * 512);
  tsplit_kernel<<<dim3(25, 8, 8), 256, 0, stream>>>(mem[1], mem1s, 256, 784, 256 * 784, 784 * 512);
  tsplit_kernel<<<dim3(98, 8, 8), 256, 0, stream>>>(mem[2], mem2s, 256, 3136, 256 * 3136, 3136 * 512);
  if (presplit)
    tsplit_kernel<<<dim3(392, 8, 8), 256, 0, stream>>>(mask_features, maskfs, 256, 12544,
                                                       (long long)256 * 12544,
                                                       (long long)12544 * 512);

  initq_kernel<<<800, 256, 0, stream>>>(qf, qe, q);

  const int Ps[3] = {196, 784, 3136};
  const int ohs[3] = {14, 28, 56};
  const int Ss[3] = {1, 2, 5};
  for (int i = 0; i < L_; ++i) {
    const int mi = i % 3, P = Ps[mi], oh = ohs[mi];
    const int Pw = (P + 31) >> 5;
    const int S = Ss[mi];
    const int ntiles = (P + KT_ - 1) / KT_;
    const int tps = (ntiles + S - 1) / S;
    if (i > 0) maskbias_kernel<<<800, 256, 0, stream>>>(out_mask, biasbits, oh);
    // ---- cross-attention ----
    mg(stream, 32, 0, 0, false, q, W2ca + (size_t)(i * 3) * 131072, ca_bqkv + i * 768, qh,
       800, 256, 256, 1, 0, 0, 0, 256);
    mg(stream, 64, 1, 0, false, memsp[mi], W2ca + (size_t)(i * 3 + 1) * 131072,
       ca_bqkv + i * 768 + 256, kvb,
       P, 512, 256, B_, (long long)P * 512, 0, (long long)P * 512, 512);
    {
      dim3 ag(64, 4, S);
      if (S > 1) {
        if (i > 0)
          fattn_kernel<true, true, true><<<ag, 256, 0, stream>>>(
              qh, 256, kvb, 512, kvb + 256, 512, biasbits, part, P, Pw, tps, S);
        else
          fattn_kernel<false, true, true><<<ag, 256, 0, stream>>>(
              qh, 256, kvb, 512, kvb + 256, 512, nullptr, part, P, Pw, tps, S);
        attncomb_kernel<<<800, 256, 0, stream>>>(part, attn_o, S, 4);
      } else {
        if (i > 0)
          fattn_kernel<true, true, false><<<ag, 256, 0, stream>>>(
              qh, 256, kvb, 512, kvb + 256, 512, biasbits, attn_o, P, Pw, tps, S);
        else
          fattn_kernel<false, true, false><<<ag, 256, 0, stream>>>(
              qh, 256, kvb, 512, kvb + 256, 512, nullptr, attn_o, P, Pw, tps, S);
      }
    }
    mg(stream, 32, 0, 0, false, attn_o, W2cao + (size_t)i * 131072, ca_bo + i * 256, tmp,
       800, 256, 256, 1, 0, 0, 0, 256);
    ln_kernel<true><<<200, 256, 0, stream>>>(tmp, q, ca_ln_s + i * 256, ca_ln_b + i * 256, q, 800);
    // ---- self-attention ----
    mg(stream, 32, 0, 0, false, q, W2sa + (size_t)(i * 3) * 131072, sa_bqkv + i * 768, qkvbuf,
       800, 768, 256, 1, 0, 0, 0, 768);
    fattn_kernel<false, false, false><<<dim3(64, 4, 1), 256, 0, stream>>>(
        qkvbuf, 768, qkvbuf + 256, 768, qkvbuf + 512, 768, nullptr, attn_o, 100, 4, 1, 1);
    mg(stream, 32, 0, 0, false, attn_o, W2sao + (size_t)i * 131072, sa_bo + i * 256, tmp,
       800, 256, 256, 1, 0, 0, 0, 256);
    ln_kernel<true><<<200, 256, 0, stream>>>(tmp, q, sa_ln_s + i * 256, sa_ln_b + i * 256, q, 800);
    // ---- FFN ----
    mg(stream, 32, 0, 0, true, q, W2f1 + (size_t)i * 1048576, ffn_b1 + i * 2048, ffnh,
       800, 2048, 256, 1, 0, 0, 0, 2048);
    mg(stream, 32, 0, 0, false, ffnh, W2f2 + (size_t)i * 1048576, ffn_b2 + i * 256, tmp,
       800, 256, 2048, 1, 0, 0, 0, 256);
    ln_kernel<true><<<200, 256, 0, stream>>>(tmp, q, ffn_ln_s + i * 256, ffn_ln_b + i * 256, q, 800);
    // ---- mask head ----
    ln_kernel<false><<<200, 256, 0, stream>>>(q, nullptr, dec_ln_s, dec_ln_b, nq, 800);
    mg(stream, 32, 0, 0, true, nq, W2me, me_b1, me1, 800, 256, 256, 1, 0, 0, 0, 256);
    mg(stream, 32, 0, 0, true, me1, W2me + 131072, me_b2, me2, 800, 256, 256, 1, 0, 0, 0, 256);
    mg(stream, 32, 0, 0, false, me2, W2me + 262144, me_b3, me3, 800, 256, 256, 1, 0, 0, 0, 256);
    if (presplit)
      mg(stream, 64, 0, 0, false, me3, maskfs, nullptr, out_mask,
         100, 12544, 256, B_, (long long)100 * 256, (long long)12544 * 512,
         (long long)100 * 12544, 12544);
    else
      mg(stream, 64, 0, 1, false, me3, mask_features, nullptr, out_mask,
         100, 12544, 256, B_, (long long)100 * 256, (long long)256 * 12544,
         (long long)100 * 12544, 12544);
  }
  gemm32_kernel<<<dim3(3, 13, 1), 256, 0, stream>>>(nq, cls_w, cls_b, out_logits, 800, C_, 256);
}

// Round 7
// 3352.699 us; speedup vs baseline: 1.2550x; 1.0983x over previous
//
#include <hip/hip_runtime.h>
#include <cmath>

#define B_ 8
#define Q_ 100
#define D_ 256
#define H_ 8
#define HD_ 32
#define L_ 9
#define F_ 2048
#define C_ 151
#define HM_ 112
#define PMAX_ 3136
#define KT_ 128
#define RECSZ 544   // 16 m + 16 l + 16*32 O

typedef __attribute__((ext_vector_type(4))) short s4v;
typedef __attribute__((ext_vector_type(8))) short s8v;
typedef __attribute__((ext_vector_type(4))) float f4v;

__device__ __forceinline__ unsigned short f2bf(float x) {
  unsigned int u = __float_as_uint(x);
  return (unsigned short)((u + 0x7fffu + ((u >> 16) & 1u)) >> 16);
}
__device__ __forceinline__ float bf2f(unsigned short h) {
  return __uint_as_float(((unsigned int)h) << 16);
}
__device__ __forceinline__ void split2(float x, short& h, short& l) {
  unsigned short hb = f2bf(x);
  float r = x - bf2f(hb);
  h = (short)hb;
  l = (short)f2bf(r);
}

__device__ __forceinline__ float block_sum(float v, float* red) {
  int t = threadIdx.x;
  red[t] = v; __syncthreads();
  for (int s = 128; s > 0; s >>= 1) {
    if (t < s) red[t] += red[t + s];
    __syncthreads();
  }
  float r = red[0]; __syncthreads();
  return r;
}

// ---------------- init q ----------------
__global__ __launch_bounds__(256) void initq_kernel(const float* __restrict__ qf,
                                                    const float* __restrict__ qe,
                                                    float* __restrict__ q) {
  int idx = blockIdx.x * 256 + threadIdx.x;
  int qd = idx % (Q_ * D_);
  q[idx] = qf[qd] + qe[qd];
}

// ---------------- transpose-split: fp32 [K][N] -> bf16 [N][2K] ----------------
__global__ __launch_bounds__(256) void tsplit_kernel(
    const float* __restrict__ in, short* __restrict__ out,
    int K, int N, long long ibs, long long obs) {
  __shared__ float tile[32][33];
  const int z = blockIdx.z;
  const int nb = blockIdx.x * 32, kb = blockIdx.y * 32;
  const float* I = in + (size_t)z * ibs;
  short* O = out + (size_t)z * obs;
  const int t = threadIdx.x;
  {
    const int r = t >> 3, c = (t & 7) * 4;
    const int gk = kb + r;
#pragma unroll
    for (int j = 0; j < 4; ++j) {
      int gn = nb + c + j;
      tile[r][c + j] = (gk < K && gn < N) ? I[(size_t)gk * N + gn] : 0.f;
    }
  }
  __syncthreads();
  {
    const int nr = t >> 3, kc = (t & 7) * 4;
    const int gn = nb + nr;
    if (gn < N) {
#pragma unroll
      for (int j = 0; j < 4; ++j) {
        int gk = kb + kc + j;
        if (gk < K) {
          short h, l; split2(tile[kc + j][nr], h, l);
          O[(size_t)gn * 2 * K + gk] = h;
          O[(size_t)gn * 2 * K + K + gk] = l;
        }
      }
    }
  }
}

// ---------------- MFMA frag load: rows [16][k32], row stride in shorts ----------------
__device__ __forceinline__ s8v ldfrag(const short* p) {
  s4v lo = *(const s4v*)p;
  s4v hi = *(const s4v*)(p + 16);
  return __builtin_shufflevector(lo, hi, 0, 1, 2, 3, 4, 5, 6, 7);
}

// ---------------- MFMA bf16x3 GEMM ----------------
template <int BM, int AMODE, int WMODE, bool RELU, int OUT>
__global__ __launch_bounds__(256) void mgemm_kernel(
    const void* __restrict__ Ap, const void* __restrict__ Wp,
    const float* __restrict__ bias, void* __restrict__ Cv,
    int M, int N, int K,
    long long Abs, long long Wbs, long long Cbs, int ldc) {
  constexpr int MI = BM / 32;
  __shared__ short Ah[BM * 36], Al[BM * 36], Wh[128 * 36], Wl[128 * 36];
  const int z = blockIdx.z;
  const int n0 = blockIdx.x * 128, m0 = blockIdx.y * BM;
  const int t = threadIdx.x;
  const int lane = t & 63;
  const int wave = t >> 6;
  const int wm = wave >> 1, wn = wave & 1;
  const int lr = lane & 15, lg = lane >> 4;
  f4v acc[MI][4];
#pragma unroll
  for (int i = 0; i < MI; ++i)
#pragma unroll
    for (int j = 0; j < 4; ++j) acc[i][j] = (f4v){0.f, 0.f, 0.f, 0.f};

  for (int k0 = 0; k0 < K; k0 += 32) {
    if (AMODE == 0) {
      const float* A = (const float*)Ap + (size_t)z * Abs;
      if (BM == 64) {
        const int arow = t >> 2;
        const int kc = (t & 3) * 8;
        float x[8];
        if (m0 + arow < M) {
          const float* ap = A + (size_t)(m0 + arow) * K + k0 + kc;
          *(f4v*)&x[0] = *(const f4v*)ap;
          *(f4v*)&x[4] = *(const f4v*)(ap + 4);
        } else {
#pragma unroll
          for (int e = 0; e < 8; ++e) x[e] = 0.f;
        }
        s4v h0, h1, l0, l1;
#pragma unroll
        for (int e = 0; e < 4; ++e) { short hh, ll; split2(x[e], hh, ll); h0[e] = hh; l0[e] = ll; }
#pragma unroll
        for (int e = 0; e < 4; ++e) { short hh, ll; split2(x[4 + e], hh, ll); h1[e] = hh; l1[e] = ll; }
        *(s4v*)&Ah[arow * 36 + kc] = h0; *(s4v*)&Ah[arow * 36 + kc + 4] = h1;
        *(s4v*)&Al[arow * 36 + kc] = l0; *(s4v*)&Al[arow * 36 + kc + 4] = l1;
      } else {
        const int arow = t >> 3;
        const int kc = (t & 7) * 4;
        float x[4];
        if (m0 + arow < M) {
          *(f4v*)&x[0] = *(const f4v*)(A + (size_t)(m0 + arow) * K + k0 + kc);
        } else {
#pragma unroll
          for (int e = 0; e < 4; ++e) x[e] = 0.f;
        }
        s4v h0, l0;
#pragma unroll
        for (int e = 0; e < 4; ++e) { short hh, ll; split2(x[e], hh, ll); h0[e] = hh; l0[e] = ll; }
        *(s4v*)&Ah[arow * 36 + kc] = h0;
        *(s4v*)&Al[arow * 36 + kc] = l0;
      }
    } else {
      const short* A2 = (const short*)Ap + (size_t)z * Abs;
      const int arow = t >> 2;
      const int c = t & 3, sel = c >> 1, ko = (c & 1) * 16;
      s8v v0 = {0, 0, 0, 0, 0, 0, 0, 0}, v1 = {0, 0, 0, 0, 0, 0, 0, 0};
      if (m0 + arow < M) {
        const short* ap = A2 + (size_t)(m0 + arow) * (2 * K) + sel * K + k0 + ko;
        v0 = *(const s8v*)ap;
        v1 = *(const s8v*)(ap + 8);
      }
      short* dst = sel ? Al : Ah;
      *(s4v*)&dst[arow * 36 + ko] = __builtin_shufflevector(v0, v0, 0, 1, 2, 3);
      *(s4v*)&dst[arow * 36 + ko + 4] = __builtin_shufflevector(v0, v0, 4, 5, 6, 7);
      *(s4v*)&dst[arow * 36 + ko + 8] = __builtin_shufflevector(v1, v1, 0, 1, 2, 3);
      *(s4v*)&dst[arow * 36 + ko + 12] = __builtin_shufflevector(v1, v1, 4, 5, 6, 7);
    }
    if (WMODE == 0) {
      const short* W2 = (const short*)Wp + (size_t)z * Wbs;
      const int n = t >> 1, sel = t & 1;
      const short* wp = W2 + (size_t)(n0 + n) * (2 * K) + sel * K + k0;
      short* dst = sel ? Wl : Wh;
#pragma unroll
      for (int j = 0; j < 4; ++j) {
        s8v v = *(const s8v*)(wp + j * 8);
        *(s4v*)&dst[n * 36 + j * 8] = __builtin_shufflevector(v, v, 0, 1, 2, 3);
        *(s4v*)&dst[n * 36 + j * 8 + 4] = __builtin_shufflevector(v, v, 4, 5, 6, 7);
      }
    } else {
      const float* W = (const float*)Wp + (size_t)z * Wbs;
      const int kr = t >> 3, c0 = (t & 7) * 16;
      const float* wp = W + (size_t)(k0 + kr) * N + n0 + c0;
      float x[16];
#pragma unroll
      for (int j = 0; j < 4; ++j) *(f4v*)&x[j * 4] = *(const f4v*)(wp + j * 4);
#pragma unroll
      for (int j = 0; j < 16; ++j) {
        short hh, ll; split2(x[j], hh, ll);
        Wh[(c0 + j) * 36 + kr] = hh;
        Wl[(c0 + j) * 36 + kr] = ll;
      }
    }
    __syncthreads();
    s8v whf[4], wlf[4];
#pragma unroll
    for (int ni = 0; ni < 4; ++ni) {
      whf[ni] = ldfrag(&Wh[(wn * 64 + ni * 16 + lr) * 36 + 4 * lg]);
      wlf[ni] = ldfrag(&Wl[(wn * 64 + ni * 16 + lr) * 36 + 4 * lg]);
    }
#pragma unroll
    for (int mi = 0; mi < MI; ++mi) {
      s8v ah = ldfrag(&Ah[(wm * (BM / 2) + mi * 16 + lr) * 36 + 4 * lg]);
      s8v al = ldfrag(&Al[(wm * (BM / 2) + mi * 16 + lr) * 36 + 4 * lg]);
#pragma unroll
      for (int ni = 0; ni < 4; ++ni) {
        acc[mi][ni] = __builtin_amdgcn_mfma_f32_16x16x32_bf16(ah, whf[ni], acc[mi][ni], 0, 0, 0);
        acc[mi][ni] = __builtin_amdgcn_mfma_f32_16x16x32_bf16(al, whf[ni], acc[mi][ni], 0, 0, 0);
        acc[mi][ni] = __builtin_amdgcn_mfma_f32_16x16x32_bf16(ah, wlf[ni], acc[mi][ni], 0, 0, 0);
      }
    }
    __syncthreads();
  }
  float* Cf = (float*)Cv + (size_t)z * Cbs;
  unsigned short* Ch = (unsigned short*)Cv + (size_t)z * Cbs;
#pragma unroll
  for (int mi = 0; mi < MI; ++mi) {
#pragma unroll
    for (int i = 0; i < 4; ++i) {
      int row = m0 + wm * (BM / 2) + mi * 16 + 4 * lg + i;
      if (row >= M) continue;
#pragma unroll
      for (int ni = 0; ni < 4; ++ni) {
        int col = n0 + wn * 64 + ni * 16 + lr;
        float v = acc[mi][ni][i] + (bias ? bias[col] : 0.f);
        if (RELU) v = fmaxf(v, 0.f);
        if (OUT == 0) Cf[(size_t)row * ldc + col] = v;
        else Ch[(size_t)row * ldc + col] = f2bf(v);
      }
    }
  }
}

// ---------------- fp32 GEMM (cls head only) ----------------
__global__ __launch_bounds__(256) void gemm32_kernel(
    const float* __restrict__ A, const float* __restrict__ W,
    const float* __restrict__ bias, float* __restrict__ C,
    int M, int N, int K) {
  __shared__ float As[16][65];
  __shared__ float Ws[16][65];
  const int n0 = blockIdx.x * 64, m0 = blockIdx.y * 64;
  const int t = threadIdx.x;
  const int tm = t >> 4, tn = t & 15;
  float acc[4][4] = {};
  for (int k0 = 0; k0 < K; k0 += 16) {
#pragma unroll
    for (int l = 0; l < 4; ++l) {
      int idx = t + l * 256;
      int am = idx >> 4, ak = idx & 15;
      int gm = m0 + am, gk = k0 + ak;
      As[ak][am] = (gm < M) ? A[(size_t)gm * K + gk] : 0.f;
      int wk = idx >> 6, wn = idx & 63;
      int gn = n0 + wn, gk2 = k0 + wk;
      Ws[wk][wn] = (gn < N) ? W[(size_t)gk2 * N + gn] : 0.f;
    }
    __syncthreads();
#pragma unroll
    for (int kk = 0; kk < 16; ++kk) {
      float a[4], b[4];
#pragma unroll
      for (int i = 0; i < 4; ++i) a[i] = As[kk][tm * 4 + i];
#pragma unroll
      for (int j = 0; j < 4; ++j) b[j] = Ws[kk][tn * 4 + j];
#pragma unroll
      for (int i = 0; i < 4; ++i)
#pragma unroll
        for (int j = 0; j < 4; ++j) acc[i][j] += a[i] * b[j];
    }
    __syncthreads();
  }
#pragma unroll
  for (int i = 0; i < 4; ++i) {
    int gm = m0 + tm * 4 + i;
    if (gm >= M) continue;
#pragma unroll
    for (int j = 0; j < 4; ++j) {
      int gn = n0 + tn * 4 + j;
      if (gn >= N) continue;
      C[(size_t)gm * N + gn] = acc[i][j] + bias[gn];
    }
  }
}

// ---------------- residual + LN: one wave per row ----------------
template <bool RES>
__global__ __launch_bounds__(256) void ln_kernel(const float* __restrict__ x,
                                                 const float* __restrict__ r,
                                                 const float* __restrict__ s,
                                                 const float* __restrict__ b,
                                                 float* __restrict__ out, int nrows) {
  const int wave = threadIdx.x >> 6, lane = threadIdx.x & 63;
  const int row = blockIdx.x * 4 + wave;
  if (row >= nrows) return;
  f4v v = *((const f4v*)(x + (size_t)row * D_) + lane);
  if (RES) {
    f4v rv = *((const f4v*)(r + (size_t)row * D_) + lane);
    v[0] += rv[0]; v[1] += rv[1]; v[2] += rv[2]; v[3] += rv[3];
  }
  float sum = v[0] + v[1] + v[2] + v[3];
#pragma unroll
  for (int off = 32; off > 0; off >>= 1) sum += __shfl_xor(sum, off, 64);
  float mean = sum * (1.f / D_);
  float c0 = v[0] - mean, c1 = v[1] - mean, c2 = v[2] - mean, c3 = v[3] - mean;
  float vs = c0 * c0 + c1 * c1 + c2 * c2 + c3 * c3;
#pragma unroll
  for (int off = 32; off > 0; off >>= 1) vs += __shfl_xor(vs, off, 64);
  float inv = rsqrtf(vs * (1.f / D_) + 1e-5f);
  f4v sv = *((const f4v*)s + lane);
  f4v bv = *((const f4v*)b + lane);
  f4v o;
  o[0] = c0 * inv * sv[0] + bv[0];
  o[1] = c1 * inv * sv[1] + bv[1];
  o[2] = c2 * inv * sv[2] + bv[2];
  o[3] = c3 * inv * sv[3] + bv[3];
  *((f4v*)(out + (size_t)row * D_) + lane) = o;
}

// ---------------- MFMA flash attention ----------------
// grid (64 = b*8+h, 7 q-tiles of 16, S). 256 thr = 4 waves; wave w owns keys
// [w*32, w*32+32) of each 128-key tile, with private online (m,l,O).
// QK^T: mfma(Qh,K)+mfma(Ql,K); PV: mfma(Pbf16, V^T staged in LDS).
template <bool BIAS, bool KVBF16, bool SPLIT>
__global__ __launch_bounds__(256) void mattn_kernel(
    const float* __restrict__ qb, int ldq,
    const void* __restrict__ kbv, int ldk,
    const void* __restrict__ vbv, int ldv,
    const unsigned int* __restrict__ bits,
    float* __restrict__ outp, int P, int Pw, int tps, int S) {
  __shared__ __align__(16) short Kt[128 * 40];   // [key][40]: 32 d + pad
  __shared__ __align__(16) short Vt[32 * 132];   // [d][132]: 128 keys + pad
  __shared__ __align__(16) short Pt[4 * 16 * 36];
  __shared__ unsigned int bb[64];                // [16 q][4 words]
  __shared__ float Msh[4][16], Lsh[4][16];
  float* Osh = (float*)Kt;                       // reused post-loop: 4*16*33*4B = 8448 <= 10240
  const int b = blockIdx.x >> 3, h = blockIdx.x & 7;
  const int q0 = blockIdx.y * 16;
  const int seg = blockIdx.z;
  const int kbeg = seg * tps * KT_;
  const int kend = min(P, kbeg + tps * KT_);
  const int t = threadIdx.x;
  const int lane = t & 63, w = t >> 6;
  const int lr = lane & 15, lg = lane >> 4;
  const float scale = 0.17677669529663687f;

  // Q fragments (bf16 h+l), rows indexed by lr
  s8v qhf, qlf;
  {
    int qrow = q0 + lr; if (qrow >= Q_) qrow = Q_ - 1;
    const float* qp = qb + (size_t)(b * Q_ + qrow) * ldq + h * HD_;
#pragma unroll
    for (int e = 0; e < 8; ++e) {
      int d = 4 * lg + (e & 3) + 16 * (e >> 2);
      short hh, ll; split2(qp[d], hh, ll);
      qhf[e] = hh; qlf[e] = ll;
    }
  }
  float mreg[4], lreg[4];
  f4v accO0 = (f4v){0.f, 0.f, 0.f, 0.f}, accO1 = (f4v){0.f, 0.f, 0.f, 0.f};
#pragma unroll
  for (int i = 0; i < 4; ++i) { mreg[i] = -3.0e38f; lreg[i] = 0.f; }

  for (int k0 = kbeg; k0 < kend; k0 += KT_) {
    // ---- stage K [key][d] and V^T [d][key] ----
    {
      const int key = t >> 1, dh = (t & 1) * 16;
      const int gk = k0 + key;
      s8v ka = {0,0,0,0,0,0,0,0}, kb2 = {0,0,0,0,0,0,0,0};
      s8v va = {0,0,0,0,0,0,0,0}, vb2 = {0,0,0,0,0,0,0,0};
      if (gk < kend) {
        if (KVBF16) {
          const unsigned short* kp = (const unsigned short*)kbv + (size_t)(b * P + gk) * ldk + h * HD_ + dh;
          const unsigned short* vp = (const unsigned short*)vbv + (size_t)(b * P + gk) * ldv + h * HD_ + dh;
          ka = *(const s8v*)kp; kb2 = *(const s8v*)(kp + 8);
          va = *(const s8v*)vp; vb2 = *(const s8v*)(vp + 8);
        } else {
          const float* kp = (const float*)kbv + (size_t)(b * P + gk) * ldk + h * HD_ + dh;
          const float* vp = (const float*)vbv + (size_t)(b * P + gk) * ldv + h * HD_ + dh;
#pragma unroll
          for (int j = 0; j < 8; ++j) {
            ka[j] = (short)f2bf(kp[j]); kb2[j] = (short)f2bf(kp[8 + j]);
            va[j] = (short)f2bf(vp[j]); vb2[j] = (short)f2bf(vp[8 + j]);
          }
        }
      }
      *(s8v*)&Kt[key * 40 + dh] = ka;
      *(s8v*)&Kt[key * 40 + dh + 8] = kb2;
#pragma unroll
      for (int j = 0; j < 8; ++j) {
        Vt[(dh + j) * 132 + key] = va[j];
        Vt[(dh + 8 + j) * 132 + key] = vb2[j];
      }
    }
    if (BIAS && t < 64) {
      int qq = t >> 2, wi = t & 3;
      int gr = q0 + qq, gw = (k0 >> 5) + wi;
      bb[t] = (gr < Q_ && gw < Pw) ? bits[(size_t)(b * Q_ + gr) * Pw + gw] : 0u;
    }
    __syncthreads();
    // ---- QK^T: 4 mfma -> S[q=4lg+i][key = w*32 + kg*16 + lr] ----
    s8v kf0 = ldfrag(&Kt[(w * 32 + lr) * 40 + 4 * lg]);
    s8v kf1 = ldfrag(&Kt[(w * 32 + 16 + lr) * 40 + 4 * lg]);
    f4v accS0 = (f4v){0.f, 0.f, 0.f, 0.f}, accS1 = (f4v){0.f, 0.f, 0.f, 0.f};
    accS0 = __builtin_amdgcn_mfma_f32_16x16x32_bf16(qhf, kf0, accS0, 0, 0, 0);
    accS0 = __builtin_amdgcn_mfma_f32_16x16x32_bf16(qlf, kf0, accS0, 0, 0, 0);
    accS1 = __builtin_amdgcn_mfma_f32_16x16x32_bf16(qhf, kf1, accS1, 0, 0, 0);
    accS1 = __builtin_amdgcn_mfma_f32_16x16x32_bf16(qlf, kf1, accS1, 0, 0, 0);
    // ---- online softmax (per wave, per 4 q-rows/lane) ----
    const int gk0 = k0 + w * 32 + lr;
#pragma unroll
    for (int i = 0; i < 4; ++i) {
      float s0 = accS0[i] * scale, s1 = accS1[i] * scale;
      if (BIAS) {
        unsigned int word = bb[(4 * lg + i) * 4 + w];
        if ((word >> lr) & 1u) s0 += -1e9f;
        if ((word >> (16 + lr)) & 1u) s1 += -1e9f;
      }
      if (gk0 >= kend) s0 = -3.0e38f;
      if (gk0 + 16 >= kend) s1 = -3.0e38f;
      float rm = fmaxf(s0, s1);
#pragma unroll
      for (int off = 1; off < 16; off <<= 1) rm = fmaxf(rm, __shfl_xor(rm, off, 64));
      float mn = fmaxf(mreg[i], rm);
      float corr = __expf(mreg[i] - mn);
      mreg[i] = mn;
      float p0 = __expf(s0 - mn), p1 = __expf(s1 - mn);
      lreg[i] = lreg[i] * corr + p0 + p1;
      accO0[i] *= corr;
      accO1[i] *= corr;
      Pt[w * 576 + (4 * lg + i) * 36 + lr] = (short)f2bf(p0);
      Pt[w * 576 + (4 * lg + i) * 36 + 16 + lr] = (short)f2bf(p1);
    }
    // ---- PV: 2 mfma ----
    s8v pf = ldfrag(&Pt[w * 576 + lr * 36 + 4 * lg]);
    s8v vf0 = ldfrag(&Vt[lr * 132 + w * 32 + 4 * lg]);
    s8v vf1 = ldfrag(&Vt[(16 + lr) * 132 + w * 32 + 4 * lg]);
    accO0 = __builtin_amdgcn_mfma_f32_16x16x32_bf16(pf, vf0, accO0, 0, 0, 0);
    accO1 = __builtin_amdgcn_mfma_f32_16x16x32_bf16(pf, vf1, accO1, 0, 0, 0);
    __syncthreads();
  }
  // ---- merge 4 waves ----
#pragma unroll
  for (int i = 0; i < 4; ++i) {
    float lv = lreg[i];
#pragma unroll
    for (int off = 1; off < 16; off <<= 1) lv += __shfl_xor(lv, off, 64);
    if (lr == 0) { Msh[w][4 * lg + i] = mreg[i]; Lsh[w][4 * lg + i] = lv; }
  }
#pragma unroll
  for (int i = 0; i < 4; ++i) {
    Osh[w * 528 + (4 * lg + i) * 33 + lr] = accO0[i];
    Osh[w * 528 + (4 * lg + i) * 33 + 16 + lr] = accO1[i];
  }
  __syncthreads();
  float* part = SPLIT
      ? outp + ((size_t)((blockIdx.x * gridDim.y + blockIdx.y) * S + seg)) * RECSZ
      : nullptr;
  for (int o = t; o < 512; o += 256) {
    int qq = o >> 5, d = o & 31;
    float M = fmaxf(fmaxf(Msh[0][qq], Msh[1][qq]), fmaxf(Msh[2][qq], Msh[3][qq]));
    float lt = 0.f, Ov = 0.f;
#pragma unroll
    for (int w4 = 0; w4 < 4; ++w4) {
      float wt = __expf(Msh[w4][qq] - M);
      lt += wt * Lsh[w4][qq];
      Ov += wt * Osh[w4 * 528 + qq * 33 + d];
    }
    if (SPLIT) {
      if (d == 0) { part[qq] = M; part[16 + qq] = lt; }
      part[32 + qq * 32 + d] = Ov;
    } else if (q0 + qq < Q_) {
      outp[(size_t)(b * Q_ + q0 + qq) * D_ + h * HD_ + d] = Ov / lt;
    }
  }
}

// ---------------- split-K combine ----------------
__global__ __launch_bounds__(256) void attncomb_kernel(
    const float* __restrict__ part, float* __restrict__ out, int S, int nqt) {
  const int row = blockIdx.x;               // b*Q + q
  const int b = row / Q_, qq = row % Q_;
  const int t = threadIdx.x;
  const int h = t >> 5, d = t & 31;
  const int qt = qq >> 4, r = qq & 15;
  const float* base = part + ((size_t)((b * 8 + h) * nqt + qt) * S) * RECSZ;
  float M = -3.0e38f;
  for (int s = 0; s < S; ++s) M = fmaxf(M, base[(size_t)s * RECSZ + r]);
  float lt = 0.f, Ov = 0.f;
  for (int s = 0; s < S; ++s) {
    const float* rec = base + (size_t)s * RECSZ;
    float w = __expf(rec[r] - M);
    lt += w * rec[16 + r];
    Ov += w * rec[32 + r * 32 + d];
  }
  out[(size_t)row * D_ + h * HD_ + d] = Ov / lt;
}

// ---------------- attention-bias from prev mask (packed bits) ----------------
__global__ __launch_bounds__(256) void maskbias_kernel(
    const float* __restrict__ prev,
    unsigned int* __restrict__ bias,
    int oh) {
  __shared__ float pm[HM_ * HM_];
  __shared__ float rbuf[PMAX_];
  __shared__ float red[256];
  __shared__ unsigned int bw[128];
  const int row = blockIdx.x;
  const int t = threadIdx.x;
  const float* src = prev + (size_t)row * (HM_ * HM_);
  for (int i = t; i < HM_ * HM_; i += 256) pm[i] = src[i];
  __syncthreads();
  const int ratio = HM_ / oh;
  const int taps = 2 * ratio;
  const float invr = 1.f / (float)ratio;
  const int P = oh * oh;
  const int Pw = (P + 31) >> 5;
  float nign = 0.f;
  for (int p = t; p < P; p += 256) {
    int oy = p / oh, ox = p - oy * oh;
    float sy = (oy + 0.5f) * ratio - 0.5f;
    float sx = (ox + 0.5f) * ratio - 0.5f;
    int y0 = (int)floorf(sy - ratio) + 1;
    int x0 = (int)floorf(sx - ratio) + 1;
    float wxs = 0.f;
    for (int si = 0; si < taps; ++si) {
      int x = x0 + si;
      if (x < 0 || x >= HM_) continue;
      wxs += 1.f - fabsf(sx - x) * invr;
    }
    float acc = 0.f, wys = 0.f;
    for (int ti = 0; ti < taps; ++ti) {
      int y = y0 + ti;
      if (y < 0 || y >= HM_) continue;
      float wy = 1.f - fabsf(sy - y) * invr;
      wys += wy;
      float ra = 0.f;
      const float* pr = pm + y * HM_;
      for (int si = 0; si < taps; ++si) {
        int x = x0 + si;
        if (x < 0 || x >= HM_) continue;
        float wx = 1.f - fabsf(sx - x) * invr;
        ra += wx * pr[x];
      }
      acc += wy * ra;
    }
    float rv = acc / (wys * wxs);
    rbuf[p] = rv;
    if (!(rv < 0.f)) nign += 1.f;
  }
  float tot = block_sum(nign, red);
  bool fully = (tot == 0.f);
  for (int w = t; w < Pw; w += 256) bw[w] = 0u;
  __syncthreads();
  if (!fully) {
    for (int p = t; p < P; p += 256) {
      if (rbuf[p] < 0.f) atomicOr(&bw[p >> 5], 1u << (p & 31));
    }
  }
  __syncthreads();
  unsigned int* dst = bias + (size_t)row * Pw;
  for (int w = t; w < Pw; w += 256) dst[w] = bw[w];
}

// ---------------- host dispatch ----------------
static inline void mg(hipStream_t st, int bm, int amode, int wmode, bool relu,
                      const void* A, const void* W, const float* bias, void* C,
                      int M, int N, int K, int Z,
                      long long Abs, long long Wbs, long long Cbs, int ldc) {
  dim3 g(N / 128, (M + bm - 1) / bm, Z);
  if (bm == 32) {
    if (relu)
      mgemm_kernel<32, 0, 0, true, 0><<<g, 256, 0, st>>>(A, W, bias, C, M, N, K, Abs, Wbs, Cbs, ldc);
    else
      mgemm_kernel<32, 0, 0, false, 0><<<g, 256, 0, st>>>(A, W, bias, C, M, N, K, Abs, Wbs, Cbs, ldc);
  } else {
    if (amode == 1)
      mgemm_kernel<64, 1, 0, false, 1><<<g, 256, 0, st>>>(A, W, bias, C, M, N, K, Abs, Wbs, Cbs, ldc);
    else if (wmode == 1)
      mgemm_kernel<64, 0, 1, false, 0><<<g, 256, 0, st>>>(A, W, bias, C, M, N, K, Abs, Wbs, Cbs, ldc);
    else
      mgemm_kernel<64, 0, 0, false, 0><<<g, 256, 0, st>>>(A, W, bias, C, M, N, K, Abs, Wbs, Cbs, ldc);
  }
}

extern "C" void kernel_launch(void* const* d_in, const int* in_sizes, int n_in,
                              void* d_out, int out_size, void* d_ws, size_t ws_size,
                              hipStream_t stream) {
  const float* mask_features = (const float*)d_in[0];
  const float* mem[3] = {(const float*)d_in[1], (const float*)d_in[2], (const float*)d_in[3]};
  const float* qf = (const float*)d_in[4];
  const float* qe = (const float*)d_in[5];
  const float* ca_wqkv = (const float*)d_in[6];
  const float* ca_bqkv = (const float*)d_in[7];
  const float* ca_wo = (const float*)d_in[8];
  const float* ca_bo = (const float*)d_in[9];
  const float* ca_ln_s = (const float*)d_in[10];
  const float* ca_ln_b = (const float*)d_in[11];
  const float* sa_wqkv = (const float*)d_in[12];
  const float* sa_bqkv = (const float*)d_in[13];
  const float* sa_wo = (const float*)d_in[14];
  const float* sa_bo = (const float*)d_in[15];
  const float* sa_ln_s = (const float*)d_in[16];
  const float* sa_ln_b = (const float*)d_in[17];
  const float* ffn_w1 = (const float*)d_in[18];
  const float* ffn_b1 = (const float*)d_in[19];
  const float* ffn_w2 = (const float*)d_in[20];
  const float* ffn_b2 = (const float*)d_in[21];
  const float* ffn_ln_s = (const float*)d_in[22];
  const float* ffn_ln_b = (const float*)d_in[23];
  const float* dec_ln_s = (const float*)d_in[24];
  const float* dec_ln_b = (const float*)d_in[25];
  const float* me_w1 = (const float*)d_in[26];
  const float* me_b1 = (const float*)d_in[27];
  const float* me_w2 = (const float*)d_in[28];
  const float* me_b2 = (const float*)d_in[29];
  const float* me_w3 = (const float*)d_in[30];
  const float* me_b3 = (const float*)d_in[31];
  const float* cls_w = (const float*)d_in[32];
  const float* cls_b = (const float*)d_in[33];

  float* out_logits = (float*)d_out;
  float* out_mask = (float*)d_out + (size_t)800 * C_;

  float* fws = (float*)d_ws;
  float* q      = fws; fws += (size_t)800 * D_;
  float* qh     = fws; fws += (size_t)800 * D_;
  float* attn_o = fws; fws += (size_t)800 * D_;
  float* tmp    = fws; fws += (size_t)800 * D_;
  float* nq     = fws; fws += (size_t)800 * D_;
  float* me1    = fws; fws += (size_t)800 * D_;
  float* me2    = fws; fws += (size_t)800 * D_;
  float* me3    = fws; fws += (size_t)800 * D_;
  float* kvbuf  = fws; fws += (size_t)B_ * PMAX_ * 256;    // bf16 [B][P][512]
  float* qkvbuf = fws; fws += (size_t)800 * 768;
  float* biasb  = fws; fws += (size_t)800 * 128;
  float* ffnh   = fws; fws += (size_t)B_ * Q_ * F_;
  float* part   = fws; fws += (size_t)64 * 7 * 3 * RECSZ;

  unsigned short* kvb = (unsigned short*)kvbuf;
  unsigned int* biasbits = (unsigned int*)biasb;

  short* sws = (short*)fws;
  short* W2ca  = sws; sws += (size_t)27 * 256 * 512;
  short* W2sa  = sws; sws += (size_t)27 * 256 * 512;
  short* W2cao = sws; sws += (size_t)9 * 256 * 512;
  short* W2sao = sws; sws += (size_t)9 * 256 * 512;
  short* W2f1  = sws; sws += (size_t)9 * 2048 * 512;
  short* W2f2  = sws; sws += (size_t)9 * 256 * 4096;
  short* W2me  = sws; sws += (size_t)3 * 256 * 512;
  short* mem2s = sws; sws += (size_t)B_ * 3136 * 512;
  short* mem1s = sws; sws += (size_t)B_ * 784 * 512;
  short* mem0s = sws; sws += (size_t)B_ * 196 * 512;
  short* memsp[3] = {mem0s, mem1s, mem2s};
  short* maskfs = sws; sws += (size_t)B_ * 12544 * 512;
  const bool presplit = ((size_t)((char*)sws - (char*)d_ws) <= ws_size);

  tsplit_kernel<<<dim3(8, 8, 27), 256, 0, stream>>>(ca_wqkv, W2ca, 256, 256, 65536, 131072);
  tsplit_kernel<<<dim3(8, 8, 27), 256, 0, stream>>>(sa_wqkv, W2sa, 256, 256, 65536, 131072);
  tsplit_kernel<<<dim3(8, 8, 9), 256, 0, stream>>>(ca_wo, W2cao, 256, 256, 65536, 131072);
  tsplit_kernel<<<dim3(8, 8, 9), 256, 0, stream>>>(sa_wo, W2sao, 256, 256, 65536, 131072);
  tsplit_kernel<<<dim3(64, 8, 9), 256, 0, stream>>>(ffn_w1, W2f1, 256, 2048, 524288, 1048576);
  tsplit_kernel<<<dim3(8, 64, 9), 256, 0, stream>>>(ffn_w2, W2f2, 2048, 256, 524288, 1048576);
  tsplit_kernel<<<dim3(8, 8, 1), 256, 0, stream>>>(me_w1, W2me, 256, 256, 0, 0);
  tsplit_kernel<<<dim3(8, 8, 1), 256, 0, stream>>>(me_w2, W2me + 131072, 256, 256, 0, 0);
  tsplit_kernel<<<dim3(8, 8, 1), 256, 0, stream>>>(me_w3, W2me + 262144, 256, 256, 0, 0);
  tsplit_kernel<<<dim3(7, 8, 8), 256, 0, stream>>>(mem[0], mem0s, 256, 196, 256 * 196, 196 * 512);
  tsplit_kernel<<<dim3(25, 8, 8), 256, 0, stream>>>(mem[1], mem1s, 256, 784, 256 * 784, 784 * 512);
  tsplit_kernel<<<dim3(98, 8, 8), 256, 0, stream>>>(mem[2], mem2s, 256, 3136, 256 * 3136, 3136 * 512);
  if (presplit)
    tsplit_kernel<<<dim3(392, 8, 8), 256, 0, stream>>>(mask_features, maskfs, 256, 12544,
                                                       (long long)256 * 12544,
                                                       (long long)12544 * 512);

  initq_kernel<<<800, 256, 0, stream>>>(qf, qe, q);

  const int Ps[3] = {196, 784, 3136};
  const int ohs[3] = {14, 28, 56};
  const int Ss[3] = {1, 2, 3};
  for (int i = 0; i < L_; ++i) {
    const int mi = i % 3, P = Ps[mi], oh = ohs[mi];
    const int Pw = (P + 31) >> 5;
    const int S = Ss[mi];
    const int ntiles = (P + KT_ - 1) / KT_;
    const int tps = (ntiles + S - 1) / S;
    if (i > 0) maskbias_kernel<<<800, 256, 0, stream>>>(out_mask, biasbits, oh);
    // ---- cross-attention ----
    mg(stream, 32, 0, 0, false, q, W2ca + (size_t)(i * 3) * 131072, ca_bqkv + i * 768, qh,
       800, 256, 256, 1, 0, 0, 0, 256);
    mg(stream, 64, 1, 0, false, memsp[mi], W2ca + (size_t)(i * 3 + 1) * 131072,
       ca_bqkv + i * 768 + 256, kvb,
       P, 512, 256, B_, (long long)P * 512, 0, (long long)P * 512, 512);
    {
      dim3 ag(64, 7, S);
      if (S > 1) {
        if (i > 0)
          mattn_kernel<true, true, true><<<ag, 256, 0, stream>>>(
              qh, 256, kvb, 512, kvb + 256, 512, biasbits, part, P, Pw, tps, S);
        else
          mattn_kernel<false, true, true><<<ag, 256, 0, stream>>>(
              qh, 256, kvb, 512, kvb + 256, 512, nullptr, part, P, Pw, tps, S);
        attncomb_kernel<<<800, 256, 0, stream>>>(part, attn_o, S, 7);
      } else {
        if (i > 0)
          mattn_kernel<true, true, false><<<ag, 256, 0, stream>>>(
              qh, 256, kvb, 512, kvb + 256, 512, biasbits, attn_o, P, Pw, tps, S);
        else
          mattn_kernel<false, true, false><<<ag, 256, 0, stream>>>(
              qh, 256, kvb, 512, kvb + 256, 512, nullptr, attn_o, P, Pw, tps, S);
      }
    }
    mg(stream, 32, 0, 0, false, attn_o, W2cao + (size_t)i * 131072, ca_bo + i * 256, tmp,
       800, 256, 256, 1, 0, 0, 0, 256);
    ln_kernel<true><<<200, 256, 0, stream>>>(tmp, q, ca_ln_s + i * 256, ca_ln_b + i * 256, q, 800);
    // ---- self-attention ----
    mg(stream, 32, 0, 0, false, q, W2sa + (size_t)(i * 3) * 131072, sa_bqkv + i * 768, qkvbuf,
       800, 768, 256, 1, 0, 0, 0, 768);
    mattn_kernel<false, false, false><<<dim3(64, 7, 1), 256, 0, stream>>>(
        qkvbuf, 768, qkvbuf + 256, 768, qkvbuf + 512, 768, nullptr, attn_o, 100, 4, 1, 1);
    mg(stream, 32, 0, 0, false, attn_o, W2sao + (size_t)i * 131072, sa_bo + i * 256, tmp,
       800, 256, 256, 1, 0, 0, 0, 256);
    ln_kernel<true><<<200, 256, 0, stream>>>(tmp, q, sa_ln_s + i * 256, sa_ln_b + i * 256, q, 800);
    // ---- FFN ----
    mg(stream, 32, 0, 0, true, q, W2f1 + (size_t)i * 1048576, ffn_b1 + i * 2048, ffnh,
       800, 2048, 256, 1, 0, 0, 0, 2048);
    mg(stream, 32, 0, 0, false, ffnh, W2f2 + (size_t)i * 1048576, ffn_b2 + i * 256, tmp,
       800, 256, 2048, 1, 0, 0, 0, 256);
    ln_kernel<true><<<200, 256, 0, stream>>>(tmp, q, ffn_ln_s + i * 256, ffn_ln_b + i * 256, q, 800);
    // ---- mask head ----
    ln_kernel<false><<<200, 256, 0, stream>>>(q, nullptr, dec_ln_s, dec_ln_b, nq, 800);
    mg(stream, 32, 0, 0, true, nq, W2me, me_b1, me1, 800, 256, 256, 1, 0, 0, 0, 256);
    mg(stream, 32, 0, 0, true, me1, W2me + 131072, me_b2, me2, 800, 256, 256, 1, 0, 0, 0, 256);
    mg(stream, 32, 0, 0, false, me2, W2me + 262144, me_b3, me3, 800, 256, 256, 1, 0, 0, 0, 256);
    if (presplit)
      mg(stream, 64, 0, 0, false, me3, maskfs, nullptr, out_mask,
         100, 12544, 256, B_, (long long)100 * 256, (long long)12544 * 512,
         (long long)100 * 12544, 12544);
    else
      mg(stream, 64, 0, 1, false, me3, mask_features, nullptr, out_mask,
         100, 12544, 256, B_, (long long)100 * 256, (long long)256 * 12544,
         (long long)100 * 12544, 12544);
  }
  gemm32_kernel<<<dim3(3, 13, 1), 256, 0, stream>>>(nq, cls_w, cls_b, out_logits, 800, C_, 256);
}